// Round 13
// baseline (116.617 us; speedup 1.0000x reference)
//
#include <hip/hip_runtime.h>
#include <math.h>

#define EMB 128
#define MAXEV 4096
#define GEV 16            // events per fused-GRU block

struct Hdr { int nl0; int nl1; int nl2; int ncomp3; };

typedef __attribute__((ext_vector_type(8))) short bf16x8;
typedef __attribute__((ext_vector_type(4))) float f32x4;

__device__ __forceinline__ float sigmoidf_(float x) { return 1.0f / (1.0f + expf(-x)); }
__device__ __forceinline__ float softplusf_(float x) {
    return (x > 0.f) ? x + log1pf(expf(-x)) : log1pf(expf(x));
}
__device__ __forceinline__ unsigned short f2bf(float f) {
    unsigned int u = __float_as_uint(f);
    u += 0x7FFFu + ((u >> 16) & 1u);          // round-to-nearest-even
    return (unsigned short)(u >> 16);
}
__device__ __forceinline__ float bf2f(unsigned short s) {
    return __uint_as_float((unsigned int)s << 16);
}

// ---------------------------------------------------------------------------
// Kernel 1 (fused): per-event prev-id search + one-shot weight->bf16 convert.
// ---------------------------------------------------------------------------
__global__ __launch_bounds__(64) void prev_kernel(
    const int* __restrict__ uids, const int* __restrict__ iids,
    int* __restrict__ prevu, int* __restrict__ previ, int nev,
    const float* __restrict__ Wuh, const float* __restrict__ Wii,
    const float* __restrict__ Wui, const float* __restrict__ Wih,
    const float* __restrict__ T1w, const float* __restrict__ T2w,
    unsigned short* __restrict__ wb_uh, unsigned short* __restrict__ wb_ii,
    unsigned short* __restrict__ wb_ui, unsigned short* __restrict__ wb_ih,
    unsigned short* __restrict__ t1wb, unsigned short* __restrict__ t2wb)
{
    int t = blockIdx.x;
    int lane = threadIdx.x;

    {   // weight conversion: 49152 (4x GRU) + 8192 (T1w) + 1024 (T2w) f4
        int gid = t * 64 + lane;
        if (gid < 58368) {
            const float* src; unsigned short* dst; int q;
            if (gid < 49152) {
                int m = gid / 12288; q = gid - m * 12288;
                src = (m == 0) ? Wuh : (m == 1) ? Wii : (m == 2) ? Wui : Wih;
                dst = (m == 0) ? wb_uh : (m == 1) ? wb_ii : (m == 2) ? wb_ui : wb_ih;
            } else if (gid < 57344) { q = gid - 49152; src = T1w; dst = t1wb; }
            else                    { q = gid - 57344; src = T2w; dst = t2wb; }
            float4 v = ((const float4*)src)[q];
            *(ushort4*)(dst + (size_t)q * 4) =
                make_ushort4(f2bf(v.x), f2bf(v.y), f2bf(v.z), f2bf(v.w));
        }
    }

    if (t >= nev) return;
    int myu = uids[t], myi = iids[t];
    int bu = -1, bi = -1;
    for (int j = lane; j < t; j += 64) {
        if (uids[j] == myu) bu = j;
        if (iids[j] == myi) bi = j;
    }
    for (int off = 32; off; off >>= 1) {
        bu = max(bu, __shfl_xor(bu, off));
        bi = max(bi, __shfl_xor(bi, off));
    }
    if (lane == 0) { prevu[t] = bu; previ[t] = bi; }
}

// ---------------------------------------------------------------------------
// Kernel 2 (single block): levels relaxed only over pred-having events
// (~250); partition lev0/lev1/lev2/lev>=3. Components over the lev>=3
// induced subgraph only (two lev>=3 events linked solely through a lev<=2
// node have no mutual dependency: that ancestor completes in pass A/B/C).
// ---------------------------------------------------------------------------
__global__ __launch_bounds__(1024) void setup_kernel(
    const int* __restrict__ prevu, const int* __restrict__ previ,
    int* __restrict__ order0, int* __restrict__ order1, int* __restrict__ order2,
    int* __restrict__ tail3Order, int* __restrict__ compStart,
    Hdr* __restrict__ hdr, int nev)
{
    __shared__ int   lab[MAXEV];     // component label, indexed by t
    __shared__ int   tmpT[MAXEV];    // pred-having events; later rank keys
    __shared__ int   t3l[MAXEV];     // lev>=3 list
    __shared__ short slev[MAXEV];
    __shared__ int   schanged, sn0, sn1, sn2, sn3, sntl;

    int tid = threadIdx.x;
    for (int t = tid; t < nev; t += 1024) slev[t] = 0;
    if (tid == 0) { sn0 = 0; sn1 = 0; sn2 = 0; sn3 = 0; sntl = 0; }
    __syncthreads();

    for (int t = tid; t < nev; t += 1024) {
        if (prevu[t] >= 0 || previ[t] >= 0) tmpT[atomicAdd(&sntl, 1)] = t;
        else                                 order0[atomicAdd(&sn0, 1)] = t;
    }
    __syncthreads();
    int ntl = sntl;

    // level relaxation over the tail-candidate list only
    for (int it = 0; it < nev; ++it) {
        if (tid == 0) schanged = 0;
        __syncthreads();
        for (int i = tid; i < ntl; i += 1024) {
            int t = tmpT[i];
            int pu = prevu[t], pi = previ[t];
            int nl = 0;
            if (pu >= 0) nl = slev[pu] + 1;
            if (pi >= 0) { int c = slev[pi] + 1; nl = nl > c ? nl : c; }
            if (nl > (int)slev[t]) { slev[t] = (short)nl; schanged = 1; }
        }
        __syncthreads();
        if (!schanged) break;
        __syncthreads();
    }

    for (int i = tid; i < ntl; i += 1024) {
        int t = tmpT[i];
        int l = slev[t];
        if (l == 1)      order1[atomicAdd(&sn1, 1)] = t;
        else if (l == 2) order2[atomicAdd(&sn2, 1)] = t;
        else if (l >= 3) t3l[atomicAdd(&sn3, 1)] = t;
    }
    __syncthreads();
    int n3 = sn3;

    // components over lev>=3 subgraph only
    for (int i = tid; i < n3; i += 1024) lab[t3l[i]] = t3l[i];
    __syncthreads();
    for (int it = 0; it < nev; ++it) {
        if (tid == 0) schanged = 0;
        __syncthreads();
        for (int i = tid; i < n3; i += 1024) {
            int t = t3l[i];
            int m = lab[t];
            int pu = prevu[t], pi = previ[t];
            bool eu = (pu >= 0 && slev[pu] >= 3);
            bool ei = (pi >= 0 && slev[pi] >= 3);
            if (eu) m = min(m, lab[pu]);
            if (ei) m = min(m, lab[pi]);
            if (m < lab[t]) { atomicMin(&lab[t], m); schanged = 1; }
            if (eu && m < lab[pu]) { atomicMin(&lab[pu], m); schanged = 1; }
            if (ei && m < lab[pi]) { atomicMin(&lab[pi], m); schanged = 1; }
        }
        __syncthreads();
        if (!schanged) break;
        __syncthreads();
    }

    // rank-sort lev>=3 by (lab, t)
    for (int i = tid; i < n3; i += 1024) tmpT[i] = (lab[t3l[i]] << 12) | t3l[i];
    __syncthreads();
    for (int i = tid; i < n3; i += 1024) {
        int k = tmpT[i], r = 0;
        for (int j = 0; j < n3; ++j) r += (tmpT[j] < k);
        tail3Order[r] = k & 0xFFF;
    }
    __syncthreads();

    if (tid == 0) {
        int nc = 0;
        for (int i = 0; i < n3; ++i)
            if (i == 0 || lab[tail3Order[i]] != lab[tail3Order[i - 1]])
                compStart[nc++] = i;
        compStart[nc] = n3;
        hdr->ncomp3 = nc;
        hdr->nl0 = sn0;
        hdr->nl1 = sn1;
        hdr->nl2 = sn2;
    }
}

// ---------------------------------------------------------------------------
// Kernel 3 (passes A/B/C, FUSED): gather -> gate MFMA -> GRU combine.
// Block = 16 events, 4 waves. bf16 u,v staged in LDS (stride 136 shorts ->
// 2-way bank conflict = free). gg pad 772 breaks 768-stride alignment.
// NUr/NVr alias NU/NV (no restrict): pass k reads only rows written by
// passes <k (cross-launch, stream-ordered).
// ---------------------------------------------------------------------------
__global__ __launch_bounds__(256) void gru_fused_kernel(
    const float* __restrict__ U0, const float* __restrict__ V0,
    const unsigned short* __restrict__ wb_ui, const unsigned short* __restrict__ wb_uh,
    const unsigned short* __restrict__ wb_ii, const unsigned short* __restrict__ wb_ih,
    const float* __restrict__ bui, const float* __restrict__ buh,
    const float* __restrict__ bii, const float* __restrict__ bih,
    const int* __restrict__ uids, const int* __restrict__ iids,
    const int* __restrict__ prevu, const int* __restrict__ previ,
    const float* NUr, const float* NVr,
    const int* __restrict__ order, const int* __restrict__ cnt_p,
    float* NU, float* NV)
{
    __shared__ __align__(16) unsigned short xbu[GEV][136];
    __shared__ __align__(16) unsigned short xbv[GEV][136];
    __shared__ float gg[GEV][772];

    int cnt = *cnt_p;
    int e0 = blockIdx.x * GEV;
    if (e0 >= cnt) return;

    int tid = threadIdx.x;
    int ev = tid >> 4, c8 = (tid & 15) * 8;

    {   // stage: 16 threads per event, 8 channels each; zero-pad beyond cnt
        int e = e0 + ev;
        float4 a0, a1, c0, c1;
        if (e < cnt) {
            int t = order[e];
            int pu = prevu[t], pi = previ[t];
            const float* up = (pu < 0 ? U0 + (size_t)uids[t] * EMB : NUr + (size_t)pu * EMB) + c8;
            const float* vp = (pi < 0 ? V0 + (size_t)iids[t] * EMB : NVr + (size_t)pi * EMB) + c8;
            a0 = ((const float4*)up)[0]; a1 = ((const float4*)up)[1];
            c0 = ((const float4*)vp)[0]; c1 = ((const float4*)vp)[1];
        } else {
            a0 = make_float4(0.f, 0.f, 0.f, 0.f); a1 = a0; c0 = a0; c1 = a0;
        }
        *(ushort4*)&xbu[ev][c8]     = make_ushort4(f2bf(a0.x), f2bf(a0.y), f2bf(a0.z), f2bf(a0.w));
        *(ushort4*)&xbu[ev][c8 + 4] = make_ushort4(f2bf(a1.x), f2bf(a1.y), f2bf(a1.z), f2bf(a1.w));
        *(ushort4*)&xbv[ev][c8]     = make_ushort4(f2bf(c0.x), f2bf(c0.y), f2bf(c0.z), f2bf(c0.w));
        *(ushort4*)&xbv[ev][c8 + 4] = make_ushort4(f2bf(c1.x), f2bf(c1.y), f2bf(c1.z), f2bf(c1.w));
    }
    __syncthreads();

    int w = tid >> 6, l = tid & 63;
    int lr = l & 15, lk = (l >> 4) * 8;

    for (int ph = 0; ph < 2; ++ph) {
        const unsigned short* Wi = ph ? wb_ii : wb_ui;
        const unsigned short* Wh = ph ? wb_ih : wb_uh;
        const unsigned short (*Xi)[136] = ph ? xbu : xbv;
        const unsigned short (*Xh)[136] = ph ? xbv : xbu;

        f32x4 acc[12] = {};
        #pragma unroll
        for (int kk = 0; kk < 4; ++kk) {
            bf16x8 ai = *(const bf16x8*)&Xi[lr][kk * 32 + lk];
            bf16x8 ah = *(const bf16x8*)&Xh[lr][kk * 32 + lk];
            #pragma unroll
            for (int j = 0; j < 12; ++j) {
                int nt = w * 12 + j;
                bool ish = nt >= 24;
                int brow = (ish ? nt - 24 : nt) * 16 + lr;
                const unsigned short* W = ish ? Wh : Wi;
                bf16x8 b = *(const bf16x8*)(W + (size_t)brow * EMB + kk * 32 + lk);
                acc[j] = __builtin_amdgcn_mfma_f32_16x16x32_bf16(ish ? ah : ai, b, acc[j], 0, 0, 0);
            }
        }
        #pragma unroll
        for (int j = 0; j < 12; ++j) {
            int nt = w * 12 + j;
            #pragma unroll
            for (int i = 0; i < 4; ++i)
                gg[(l >> 4) * 4 + i][nt * 16 + lr] = acc[j][i];
        }
        __syncthreads();

        {   // combine (gg[ev][0..383]=gi, [384..767]=gh)
            int e = e0 + ev;
            if (e < cnt) {
                int t = order[e];
                const float* bi = ph ? bii : bui;
                const float* bh = ph ? bih : buh;
                float* N = ph ? NV : NU;
                const unsigned short (*xh)[136] = ph ? xbv : xbu;
                #pragma unroll
                for (int i = 0; i < 8; ++i) {
                    int ch = c8 + i;
                    float r_ = sigmoidf_(gg[ev][ch] + bi[ch] + gg[ev][384 + ch] + bh[ch]);
                    float z_ = sigmoidf_(gg[ev][128 + ch] + bi[128 + ch] + gg[ev][512 + ch] + bh[128 + ch]);
                    float n_ = tanhf(gg[ev][256 + ch] + bi[256 + ch] + r_ * (gg[ev][640 + ch] + bh[256 + ch]));
                    float h = bf2f(xh[ev][ch]);
                    N[(size_t)t * EMB + ch] = (1.f - z_) * n_ + z_ * h;
                }
            }
        }
        __syncthreads();
    }
}

// ---------------------------------------------------------------------------
// Kernel 4: lev>=3 events (~5), fp32, component-serial, 1024 threads.
// #pragma unroll 1 on the batch loop is LOAD-BEARING (rounds 5/6: full unroll
// -> 768 live regs -> scratch spill -> 100% spill-BW-bound).
// ---------------------------------------------------------------------------
__global__ __launch_bounds__(1024) void tail3_kernel(
    const float* __restrict__ U0,  const float* __restrict__ V0,
    const float* __restrict__ Wui, const float* __restrict__ Wuh,
    const float* __restrict__ bui, const float* __restrict__ buh,
    const float* __restrict__ Wii, const float* __restrict__ Wih,
    const float* __restrict__ bii, const float* __restrict__ bih,
    const int* __restrict__ uids,  const int* __restrict__ iids,
    const int* __restrict__ prevu, const int* __restrict__ previ,
    const int* __restrict__ tail3Order, const int* __restrict__ compStart,
    const Hdr* __restrict__ hdr,
    float* __restrict__ NU, float* __restrict__ NV)
{
    __shared__ __align__(16) float su[EMB];
    __shared__ __align__(16) float sv[EMB];
    __shared__ float gg[1536];
    int tid = threadIdx.x;
    int ncomp = hdr->ncomp3;

    int g = tid >> 4, j = tid & 15;
    int mat = g >> 4;
    const float* W = (mat == 0) ? Wui : (mat == 1) ? Wuh : (mat == 2) ? Wii : Wih;

    for (int c = blockIdx.x; c < ncomp; c += gridDim.x) {
        int kb = compStart[c], ke = compStart[c + 1];
        for (int k = kb; k < ke; ++k) {
            int t = tail3Order[k];
            int pu = prevu[t], pi = previ[t];
            const float* up = (pu < 0) ? U0 + (size_t)uids[t] * EMB : NU + (size_t)pu * EMB;
            const float* vp = (pi < 0) ? V0 + (size_t)iids[t] * EMB : NV + (size_t)pi * EMB;
            __syncthreads();
            if (tid < EMB)        su[tid] = up[tid];
            else if (tid < 2*EMB) sv[tid - EMB] = vp[tid - EMB];
            __syncthreads();

            const float* x = (mat == 1 || mat == 2) ? su : sv;
            const float4* x4 = (const float4*)x;
            float4 xa = x4[2 * j], xb = x4[2 * j + 1];
            #pragma unroll 1
            for (int b = 0; b < 3; ++b) {
                int rbase = (g & 15) * 24 + b * 8;
                float4 w0[8], w1[8];
                #pragma unroll
                for (int q = 0; q < 8; ++q) {
                    const float4* W4 = (const float4*)(W + (size_t)(rbase + q) * EMB);
                    w0[q] = W4[2 * j]; w1[q] = W4[2 * j + 1];
                }
                #pragma unroll
                for (int q = 0; q < 8; ++q) {
                    float s = w0[q].x * xa.x + w0[q].y * xa.y
                            + w0[q].z * xa.z + w0[q].w * xa.w
                            + w1[q].x * xb.x + w1[q].y * xb.y
                            + w1[q].z * xb.z + w1[q].w * xb.w;
                    s += __shfl_xor(s, 1); s += __shfl_xor(s, 2);
                    s += __shfl_xor(s, 4); s += __shfl_xor(s, 8);
                    if (j == q) gg[mat * 384 + rbase + q] = s;
                }
            }
            __syncthreads();

            if (tid < EMB) {
                int e = tid;
                float r_ = sigmoidf_(gg[e] + bui[e] + gg[384 + e] + buh[e]);
                float z_ = sigmoidf_(gg[128 + e] + bui[128 + e] + gg[512 + e] + buh[128 + e]);
                float n_ = tanhf(gg[256 + e] + bui[256 + e] + r_ * (gg[640 + e] + buh[256 + e]));
                NU[(size_t)t * EMB + e] = (1.f - z_) * n_ + z_ * su[e];
            } else if (tid < 2*EMB) {
                int e = tid - EMB;
                float r_ = sigmoidf_(gg[768 + e] + bii[e] + gg[1152 + e] + bih[e]);
                float z_ = sigmoidf_(gg[896 + e] + bii[128 + e] + gg[1280 + e] + bih[128 + e]);
                float n_ = tanhf(gg[1024 + e] + bii[256 + e] + r_ * (gg[1408 + e] + bih[256 + e]));
                NV[(size_t)t * EMB + e] = (1.f - z_) * n_ + z_ * sv[e];
            }
        }
    }
}

// ---------------------------------------------------------------------------
// Kernel 5 (FUSED post): gather+loss -> T1 MFMA -> h1(bf16,LDS) -> T2 MFMA
// -> T3+sigmoid. Block = 64 events, 4 waves.
// ---------------------------------------------------------------------------
__global__ __launch_bounds__(256) void post_fused_kernel(
    const float* __restrict__ U0, const float* __restrict__ V0,
    const int* __restrict__ uids, const int* __restrict__ iids,
    const int* __restrict__ prevu, const int* __restrict__ previ,
    const float* __restrict__ NU, const float* __restrict__ NV,
    const unsigned short* __restrict__ t1wb, const float* __restrict__ T1b,
    const unsigned short* __restrict__ t2wb, const float* __restrict__ T2b,
    const float* __restrict__ T3w, const float* __restrict__ T3b,
    float* __restrict__ out, int nev)
{
    __shared__ __align__(16) unsigned short xau[64][136];
    __shared__ __align__(16) unsigned short xav[64][136];
    __shared__ __align__(16) unsigned short h1b[64][136];
    __shared__ float h2s[64][36];

    int tid = threadIdx.x;
    int ev0 = blockIdx.x * 64;

    // ---- stage (bf16) + loss ----
    #pragma unroll
    for (int rep = 0; rep < 4; ++rep) {
        int idx = rep * 256 + tid;
        int evl = idx >> 4, j16 = idx & 15;
        int t = ev0 + evl;
        float4 a0, a1, c0, c1;
        if (t < nev) {
            int pu = prevu[t], pi = previ[t];
            const float* up = (pu < 0 ? U0 + (size_t)uids[t] * EMB : NU + (size_t)pu * EMB) + j16 * 8;
            const float* vp = (pi < 0 ? V0 + (size_t)iids[t] * EMB : NV + (size_t)pi * EMB) + j16 * 8;
            a0 = ((const float4*)up)[0]; a1 = ((const float4*)up)[1];
            c0 = ((const float4*)vp)[0]; c1 = ((const float4*)vp)[1];
        } else {
            a0 = make_float4(0.f, 0.f, 0.f, 0.f); a1 = a0; c0 = a0; c1 = a0;
        }
        *(ushort4*)&xau[evl][j16 * 8]     = make_ushort4(f2bf(a0.x), f2bf(a0.y), f2bf(a0.z), f2bf(a0.w));
        *(ushort4*)&xau[evl][j16 * 8 + 4] = make_ushort4(f2bf(a1.x), f2bf(a1.y), f2bf(a1.z), f2bf(a1.w));
        *(ushort4*)&xav[evl][j16 * 8]     = make_ushort4(f2bf(c0.x), f2bf(c0.y), f2bf(c0.z), f2bf(c0.w));
        *(ushort4*)&xav[evl][j16 * 8 + 4] = make_ushort4(f2bf(c1.x), f2bf(c1.y), f2bf(c1.z), f2bf(c1.w));
        float dp = a0.x * c0.x + a0.y * c0.y + a0.z * c0.z + a0.w * c0.w
                 + a1.x * c1.x + a1.y * c1.y + a1.z * c1.z + a1.w * c1.w;
        dp += __shfl_xor(dp, 1); dp += __shfl_xor(dp, 2);
        dp += __shfl_xor(dp, 4); dp += __shfl_xor(dp, 8);
        if (j16 == 0 && t < nev)
            out[2 * (size_t)t] = -logf(softplusf_(dp) + 1e-10f);
    }
    __syncthreads();

    int w = tid >> 6, l = tid & 63;
    int lr = l & 15, lk = (l >> 4) * 8;

    // ---- T1: 128 cols, K=256 ([u|v]) ----
    {
        f32x4 acc[8] = {};
        #pragma unroll
        for (int kh = 0; kh < 8; ++kh) {
            const unsigned short* ar = (kh < 4)
                ? &xau[w * 16 + lr][kh * 32 + lk]
                : &xav[w * 16 + lr][(kh - 4) * 32 + lk];
            bf16x8 a = *(const bf16x8*)ar;
            #pragma unroll
            for (int n = 0; n < 8; ++n) {
                bf16x8 b = *(const bf16x8*)(t1wb + (size_t)(n * 16 + lr) * 256 + kh * 32 + lk);
                acc[n] = __builtin_amdgcn_mfma_f32_16x16x32_bf16(a, b, acc[n], 0, 0, 0);
            }
        }
        #pragma unroll
        for (int n = 0; n < 8; ++n) {
            int col = n * 16 + lr;
            float bb = T1b[col];
            #pragma unroll
            for (int i = 0; i < 4; ++i)
                h1b[w * 16 + (l >> 4) * 4 + i][col] = f2bf(fmaxf(acc[n][i] + bb, 0.f));
        }
    }
    __syncthreads();

    // ---- T2: 32 cols, K=128 ----
    {
        f32x4 acc2[2] = {};
        #pragma unroll
        for (int kk = 0; kk < 4; ++kk) {
            bf16x8 a = *(const bf16x8*)&h1b[w * 16 + lr][kk * 32 + lk];
            #pragma unroll
            for (int n = 0; n < 2; ++n) {
                bf16x8 b = *(const bf16x8*)(t2wb + (size_t)(n * 16 + lr) * 128 + kk * 32 + lk);
                acc2[n] = __builtin_amdgcn_mfma_f32_16x16x32_bf16(a, b, acc2[n], 0, 0, 0);
            }
        }
        #pragma unroll
        for (int n = 0; n < 2; ++n) {
            int col = n * 16 + lr;
            float bb = T2b[col];
            #pragma unroll
            for (int i = 0; i < 4; ++i)
                h2s[w * 16 + (l >> 4) * 4 + i][col] = fmaxf(acc2[n][i] + bb, 0.f);
        }
    }
    __syncthreads();

    // ---- T3 + sigmoid ----
    {
        int evl = tid >> 2, q4 = tid & 3;
        float p = 0.f;
        #pragma unroll
        for (int i = 0; i < 8; ++i) {
            int ch = q4 * 8 + i;
            p = fmaf(T3w[ch], h2s[evl][ch], p);
        }
        p += __shfl_xor(p, 1); p += __shfl_xor(p, 2);
        int t = ev0 + evl;
        if (q4 == 0 && t < nev)
            out[2 * (size_t)t + 1] = sigmoidf_(p + T3b[0]);
    }
}

// ---------------------------------------------------------------------------
extern "C" void kernel_launch(void* const* d_in, const int* in_sizes, int n_in,
                              void* d_out, int out_size, void* d_ws, size_t ws_size,
                              hipStream_t stream)
{
    const float* U0  = (const float*)d_in[0];
    const float* V0  = (const float*)d_in[1];
    const float* Wui = (const float*)d_in[2];
    const float* Wuh = (const float*)d_in[3];
    const float* bui = (const float*)d_in[4];
    const float* buh = (const float*)d_in[5];
    const float* Wii = (const float*)d_in[6];
    const float* Wih = (const float*)d_in[7];
    const float* bii = (const float*)d_in[8];
    const float* bih = (const float*)d_in[9];
    const float* T1w = (const float*)d_in[10];
    const float* T1b = (const float*)d_in[11];
    const float* T2w = (const float*)d_in[12];
    const float* T2b = (const float*)d_in[13];
    const float* T3w = (const float*)d_in[14];
    const float* T3b = (const float*)d_in[15];
    const int* uids  = (const int*)d_in[16];
    const int* iids  = (const int*)d_in[17];
    int nev = in_sizes[16];

    char* ws = (char*)d_ws;
    int* base = (int*)ws;
    int* prevu      = base;                 // MAXEV
    int* previ      = base + MAXEV;         // MAXEV
    int* order0     = base + 2 * MAXEV;     // MAXEV
    int* order1     = base + 3 * MAXEV;     // MAXEV
    int* order2     = base + 4 * MAXEV;     // MAXEV
    int* tail3Order = base + 5 * MAXEV;     // MAXEV
    int* compStart  = base + 6 * MAXEV;     // MAXEV+2
    Hdr* hdr        = (Hdr*)(base + 7 * MAXEV + 4);
    float* NU = (float*)(ws + (192 << 10));              // 2 MB
    float* NV = NU + (size_t)MAXEV * EMB;                // 2 MB
    unsigned short* wb_uh = (unsigned short*)(NV + (size_t)MAXEV * EMB);
    unsigned short* wb_ii = wb_uh + 384 * EMB;           // 96 KB each
    unsigned short* wb_ui = wb_ii + 384 * EMB;
    unsigned short* wb_ih = wb_ui + 384 * EMB;
    unsigned short* t1wb  = wb_ih + 384 * EMB;           // 64 KB
    unsigned short* t2wb  = t1wb + EMB * 256;            // 8 KB
    float* out = (float*)d_out;

    prev_kernel<<<MAXEV, 64, 0, stream>>>(
        uids, iids, prevu, previ, nev,
        Wuh, Wii, Wui, Wih, T1w, T2w,
        wb_uh, wb_ii, wb_ui, wb_ih, t1wb, t2wb);
    setup_kernel<<<1, 1024, 0, stream>>>(prevu, previ, order0, order1, order2,
                                         tail3Order, compStart, hdr, nev);

    // Pass A: level-0 events
    gru_fused_kernel<<<MAXEV / GEV, 256, 0, stream>>>(
        U0, V0, wb_ui, wb_uh, wb_ii, wb_ih, bui, buh, bii, bih,
        uids, iids, prevu, previ, NU, NV, order0, &hdr->nl0, NU, NV);

    // Pass B: level-1 events
    gru_fused_kernel<<<MAXEV / GEV, 256, 0, stream>>>(
        U0, V0, wb_ui, wb_uh, wb_ii, wb_ih, bui, buh, bii, bih,
        uids, iids, prevu, previ, NU, NV, order1, &hdr->nl1, NU, NV);

    // Pass C: level-2 events
    gru_fused_kernel<<<MAXEV / GEV, 256, 0, stream>>>(
        U0, V0, wb_ui, wb_uh, wb_ii, wb_ih, bui, buh, bii, bih,
        uids, iids, prevu, previ, NU, NV, order2, &hdr->nl2, NU, NV);

    // lev>=3 remainder: component-serial (tiny)
    tail3_kernel<<<64, 1024, 0, stream>>>(
        U0, V0, Wui, Wuh, bui, buh, Wii, Wih, bii, bih,
        uids, iids, prevu, previ, tail3Order, compStart, hdr, NU, NV);

    // fused loss + MLP branch
    post_fused_kernel<<<(nev + 63) / 64, 256, 0, stream>>>(
        U0, V0, uids, iids, prevu, previ, NU, NV,
        t1wb, T1b, t2wb, T2b, T3w, T3b, out, nev);
}

// Round 14
// 105.504 us; speedup vs baseline: 1.1053x; 1.1053x over previous
//
#include <hip/hip_runtime.h>
#include <math.h>

#define EMB 128
#define MAXEV 4096
#define GEV 16            // events per fused-GRU block

struct Hdr { int nl0; int nl1; int ncomp2; };

typedef __attribute__((ext_vector_type(8))) short bf16x8;
typedef __attribute__((ext_vector_type(4))) float f32x4;

__device__ __forceinline__ float sigmoidf_(float x) { return 1.0f / (1.0f + expf(-x)); }
__device__ __forceinline__ float softplusf_(float x) {
    return (x > 0.f) ? x + log1pf(expf(-x)) : log1pf(expf(x));
}
__device__ __forceinline__ unsigned short f2bf(float f) {
    unsigned int u = __float_as_uint(f);
    u += 0x7FFFu + ((u >> 16) & 1u);          // round-to-nearest-even
    return (unsigned short)(u >> 16);
}
__device__ __forceinline__ float bf2f(unsigned short s) {
    return __uint_as_float((unsigned int)s << 16);
}

// ---------------------------------------------------------------------------
// Kernel 1 (fused): per-event prev-id search + one-shot weight->bf16 convert.
// ---------------------------------------------------------------------------
__global__ __launch_bounds__(64) void prev_kernel(
    const int* __restrict__ uids, const int* __restrict__ iids,
    int* __restrict__ prevu, int* __restrict__ previ, int nev,
    const float* __restrict__ Wuh, const float* __restrict__ Wii,
    const float* __restrict__ Wui, const float* __restrict__ Wih,
    const float* __restrict__ T1w, const float* __restrict__ T2w,
    unsigned short* __restrict__ wb_uh, unsigned short* __restrict__ wb_ii,
    unsigned short* __restrict__ wb_ui, unsigned short* __restrict__ wb_ih,
    unsigned short* __restrict__ t1wb, unsigned short* __restrict__ t2wb)
{
    int t = blockIdx.x;
    int lane = threadIdx.x;

    {   // weight conversion: 49152 (4x GRU) + 8192 (T1w) + 1024 (T2w) f4
        int gid = t * 64 + lane;
        if (gid < 58368) {
            const float* src; unsigned short* dst; int q;
            if (gid < 49152) {
                int m = gid / 12288; q = gid - m * 12288;
                src = (m == 0) ? Wuh : (m == 1) ? Wii : (m == 2) ? Wui : Wih;
                dst = (m == 0) ? wb_uh : (m == 1) ? wb_ii : (m == 2) ? wb_ui : wb_ih;
            } else if (gid < 57344) { q = gid - 49152; src = T1w; dst = t1wb; }
            else                    { q = gid - 57344; src = T2w; dst = t2wb; }
            float4 v = ((const float4*)src)[q];
            *(ushort4*)(dst + (size_t)q * 4) =
                make_ushort4(f2bf(v.x), f2bf(v.y), f2bf(v.z), f2bf(v.w));
        }
    }

    if (t >= nev) return;
    int myu = uids[t], myi = iids[t];
    int bu = -1, bi = -1;
    for (int j = lane; j < t; j += 64) {
        if (uids[j] == myu) bu = j;
        if (iids[j] == myi) bi = j;
    }
    for (int off = 32; off; off >>= 1) {
        bu = max(bu, __shfl_xor(bu, off));
        bi = max(bi, __shfl_xor(bi, off));
    }
    if (lane == 0) { prevu[t] = bu; previ[t] = bi; }
}

// ---------------------------------------------------------------------------
// Kernel 2 (single block): levels relaxed ONLY over pred-having events
// (~250); components ONLY over the lev>=2 induced subgraph (~15 events).
// ---------------------------------------------------------------------------
__global__ __launch_bounds__(1024) void setup_kernel(
    const int* __restrict__ prevu, const int* __restrict__ previ,
    int* __restrict__ order0, int* __restrict__ order1,
    int* __restrict__ tail2Order, int* __restrict__ compStart,
    Hdr* __restrict__ hdr, int nev)
{
    __shared__ int   lab[MAXEV];     // component label, indexed by t
    __shared__ int   tmpT[MAXEV];    // pred-having events; later rank keys
    __shared__ int   t2l[MAXEV];     // lev>=2 list
    __shared__ short slev[MAXEV];
    __shared__ int   schanged, sn0, sn1, sn2, sntl;

    int tid = threadIdx.x;
    for (int t = tid; t < nev; t += 1024) slev[t] = 0;
    if (tid == 0) { sn0 = 0; sn1 = 0; sn2 = 0; sntl = 0; }
    __syncthreads();

    for (int t = tid; t < nev; t += 1024) {
        if (prevu[t] >= 0 || previ[t] >= 0) tmpT[atomicAdd(&sntl, 1)] = t;
        else                                 order0[atomicAdd(&sn0, 1)] = t;
    }
    __syncthreads();
    int ntl = sntl;

    // level relaxation over the tail-candidate list only
    for (int it = 0; it < nev; ++it) {
        if (tid == 0) schanged = 0;
        __syncthreads();
        for (int i = tid; i < ntl; i += 1024) {
            int t = tmpT[i];
            int pu = prevu[t], pi = previ[t];
            int nl = 0;
            if (pu >= 0) nl = slev[pu] + 1;
            if (pi >= 0) { int c = slev[pi] + 1; nl = nl > c ? nl : c; }
            if (nl > (int)slev[t]) { slev[t] = (short)nl; schanged = 1; }
        }
        __syncthreads();
        if (!schanged) break;
        __syncthreads();
    }

    for (int i = tid; i < ntl; i += 1024) {
        int t = tmpT[i];
        if (slev[t] == 1)      order1[atomicAdd(&sn1, 1)] = t;
        else if (slev[t] >= 2) t2l[atomicAdd(&sn2, 1)] = t;
    }
    __syncthreads();
    int n2 = sn2;

    // components over lev>=2 subgraph only
    for (int i = tid; i < n2; i += 1024) lab[t2l[i]] = t2l[i];
    __syncthreads();
    for (int it = 0; it < nev; ++it) {
        if (tid == 0) schanged = 0;
        __syncthreads();
        for (int i = tid; i < n2; i += 1024) {
            int t = t2l[i];
            int m = lab[t];
            int pu = prevu[t], pi = previ[t];
            bool eu = (pu >= 0 && slev[pu] >= 2);
            bool ei = (pi >= 0 && slev[pi] >= 2);
            if (eu) m = min(m, lab[pu]);
            if (ei) m = min(m, lab[pi]);
            if (m < lab[t]) { atomicMin(&lab[t], m); schanged = 1; }
            if (eu && m < lab[pu]) { atomicMin(&lab[pu], m); schanged = 1; }
            if (ei && m < lab[pi]) { atomicMin(&lab[pi], m); schanged = 1; }
        }
        __syncthreads();
        if (!schanged) break;
        __syncthreads();
    }

    // rank-sort lev>=2 by (lab, t)
    for (int i = tid; i < n2; i += 1024) tmpT[i] = (lab[t2l[i]] << 12) | t2l[i];
    __syncthreads();
    for (int i = tid; i < n2; i += 1024) {
        int k = tmpT[i], r = 0;
        for (int j = 0; j < n2; ++j) r += (tmpT[j] < k);
        tail2Order[r] = k & 0xFFF;
    }
    __syncthreads();

    if (tid == 0) {
        int nc = 0;
        for (int i = 0; i < n2; ++i)
            if (i == 0 || lab[tail2Order[i]] != lab[tail2Order[i - 1]])
                compStart[nc++] = i;
        compStart[nc] = n2;
        hdr->ncomp2 = nc;
        hdr->nl0 = sn0;
        hdr->nl1 = sn1;
    }
}

// ---------------------------------------------------------------------------
// Kernel 3 (both passes, FUSED): gather -> gate MFMA -> GRU combine.
// Block = 16 events, 4 waves. bf16 u,v staged in LDS (stride 136 shorts ->
// 2-way bank conflict = free). gg pad 772 breaks 768-stride alignment.
// NUr/NVr alias NU/NV (no restrict): pass B reads only pass-A rows.
// ---------------------------------------------------------------------------
__global__ __launch_bounds__(256) void gru_fused_kernel(
    const float* __restrict__ U0, const float* __restrict__ V0,
    const unsigned short* __restrict__ wb_ui, const unsigned short* __restrict__ wb_uh,
    const unsigned short* __restrict__ wb_ii, const unsigned short* __restrict__ wb_ih,
    const float* __restrict__ bui, const float* __restrict__ buh,
    const float* __restrict__ bii, const float* __restrict__ bih,
    const int* __restrict__ uids, const int* __restrict__ iids,
    const int* __restrict__ prevu, const int* __restrict__ previ,
    const float* NUr, const float* NVr,
    const int* __restrict__ order, const int* __restrict__ cnt_p,
    float* NU, float* NV)
{
    __shared__ __align__(16) unsigned short xbu[GEV][136];
    __shared__ __align__(16) unsigned short xbv[GEV][136];
    __shared__ float gg[GEV][772];

    int cnt = *cnt_p;
    int e0 = blockIdx.x * GEV;
    if (e0 >= cnt) return;

    int tid = threadIdx.x;
    int ev = tid >> 4, c8 = (tid & 15) * 8;

    {   // stage: 16 threads per event, 8 channels each; zero-pad beyond cnt
        int e = e0 + ev;
        float4 a0, a1, c0, c1;
        if (e < cnt) {
            int t = order[e];
            int pu = prevu[t], pi = previ[t];
            const float* up = (pu < 0 ? U0 + (size_t)uids[t] * EMB : NUr + (size_t)pu * EMB) + c8;
            const float* vp = (pi < 0 ? V0 + (size_t)iids[t] * EMB : NVr + (size_t)pi * EMB) + c8;
            a0 = ((const float4*)up)[0]; a1 = ((const float4*)up)[1];
            c0 = ((const float4*)vp)[0]; c1 = ((const float4*)vp)[1];
        } else {
            a0 = make_float4(0.f, 0.f, 0.f, 0.f); a1 = a0; c0 = a0; c1 = a0;
        }
        *(ushort4*)&xbu[ev][c8]     = make_ushort4(f2bf(a0.x), f2bf(a0.y), f2bf(a0.z), f2bf(a0.w));
        *(ushort4*)&xbu[ev][c8 + 4] = make_ushort4(f2bf(a1.x), f2bf(a1.y), f2bf(a1.z), f2bf(a1.w));
        *(ushort4*)&xbv[ev][c8]     = make_ushort4(f2bf(c0.x), f2bf(c0.y), f2bf(c0.z), f2bf(c0.w));
        *(ushort4*)&xbv[ev][c8 + 4] = make_ushort4(f2bf(c1.x), f2bf(c1.y), f2bf(c1.z), f2bf(c1.w));
    }
    __syncthreads();

    int w = tid >> 6, l = tid & 63;
    int lr = l & 15, lk = (l >> 4) * 8;

    for (int ph = 0; ph < 2; ++ph) {
        const unsigned short* Wi = ph ? wb_ii : wb_ui;
        const unsigned short* Wh = ph ? wb_ih : wb_uh;
        const unsigned short (*Xi)[136] = ph ? xbu : xbv;
        const unsigned short (*Xh)[136] = ph ? xbv : xbu;

        f32x4 acc[12] = {};
        #pragma unroll
        for (int kk = 0; kk < 4; ++kk) {
            bf16x8 ai = *(const bf16x8*)&Xi[lr][kk * 32 + lk];
            bf16x8 ah = *(const bf16x8*)&Xh[lr][kk * 32 + lk];
            #pragma unroll
            for (int j = 0; j < 12; ++j) {
                int nt = w * 12 + j;
                bool ish = nt >= 24;
                int brow = (ish ? nt - 24 : nt) * 16 + lr;
                const unsigned short* W = ish ? Wh : Wi;
                bf16x8 b = *(const bf16x8*)(W + (size_t)brow * EMB + kk * 32 + lk);
                acc[j] = __builtin_amdgcn_mfma_f32_16x16x32_bf16(ish ? ah : ai, b, acc[j], 0, 0, 0);
            }
        }
        #pragma unroll
        for (int j = 0; j < 12; ++j) {
            int nt = w * 12 + j;
            #pragma unroll
            for (int i = 0; i < 4; ++i)
                gg[(l >> 4) * 4 + i][nt * 16 + lr] = acc[j][i];
        }
        __syncthreads();

        {   // combine (gg[ev][0..383]=gi, [384..767]=gh)
            int e = e0 + ev;
            if (e < cnt) {
                int t = order[e];
                const float* bi = ph ? bii : bui;
                const float* bh = ph ? bih : buh;
                float* N = ph ? NV : NU;
                const unsigned short (*xh)[136] = ph ? xbv : xbu;
                #pragma unroll
                for (int i = 0; i < 8; ++i) {
                    int ch = c8 + i;
                    float r_ = sigmoidf_(gg[ev][ch] + bi[ch] + gg[ev][384 + ch] + bh[ch]);
                    float z_ = sigmoidf_(gg[ev][128 + ch] + bi[128 + ch] + gg[ev][512 + ch] + bh[128 + ch]);
                    float n_ = tanhf(gg[ev][256 + ch] + bi[256 + ch] + r_ * (gg[ev][640 + ch] + bh[256 + ch]));
                    float h = bf2f(xh[ev][ch]);
                    N[(size_t)t * EMB + ch] = (1.f - z_) * n_ + z_ * h;
                }
            }
        }
        __syncthreads();
    }
}

// ---------------------------------------------------------------------------
// Kernel 4: lev>=2 events (~15), component-serial, 1024 threads.
// bf16 weights: one bf16x8 load per row per lane -> 2 serial batches of 12
// rows (was 3x8 with fp32). 48 VGPRs of weights in flight (< 128 cap).
// #pragma unroll 1 on the batch loop is LOAD-BEARING (rounds 5/6: full
// unroll -> reg spill -> 100% spill-BW-bound).
// ---------------------------------------------------------------------------
__global__ __launch_bounds__(1024) void tail2_kernel(
    const float* __restrict__ U0,  const float* __restrict__ V0,
    const unsigned short* __restrict__ wb_ui, const unsigned short* __restrict__ wb_uh,
    const float* __restrict__ bui, const float* __restrict__ buh,
    const unsigned short* __restrict__ wb_ii, const unsigned short* __restrict__ wb_ih,
    const float* __restrict__ bii, const float* __restrict__ bih,
    const int* __restrict__ uids,  const int* __restrict__ iids,
    const int* __restrict__ prevu, const int* __restrict__ previ,
    const int* __restrict__ tail2Order, const int* __restrict__ compStart,
    const Hdr* __restrict__ hdr,
    float* __restrict__ NU, float* __restrict__ NV)
{
    __shared__ __align__(16) float su[EMB];
    __shared__ __align__(16) float sv[EMB];
    __shared__ float gg[1536];
    int tid = threadIdx.x;
    int ncomp = hdr->ncomp2;

    int g = tid >> 4, j = tid & 15;       // 64 groups x 16 lanes
    int mat = g >> 4;                     // 16 groups per matrix
    const unsigned short* W = (mat == 0) ? wb_ui : (mat == 1) ? wb_uh
                            : (mat == 2) ? wb_ii : wb_ih;

    for (int c = blockIdx.x; c < ncomp; c += gridDim.x) {
        int kb = compStart[c], ke = compStart[c + 1];
        for (int k = kb; k < ke; ++k) {
            int t = tail2Order[k];
            int pu = prevu[t], pi = previ[t];
            const float* up = (pu < 0) ? U0 + (size_t)uids[t] * EMB : NU + (size_t)pu * EMB;
            const float* vp = (pi < 0) ? V0 + (size_t)iids[t] * EMB : NV + (size_t)pi * EMB;
            __syncthreads();
            if (tid < EMB)        su[tid] = up[tid];
            else if (tid < 2*EMB) sv[tid - EMB] = vp[tid - EMB];
            __syncthreads();

            const float* x = (mat == 1 || mat == 2) ? su : sv;
            float x8[8];
            #pragma unroll
            for (int i = 0; i < 8; ++i) x8[i] = x[j * 8 + i];

            #pragma unroll 1
            for (int b = 0; b < 2; ++b) {
                int rbase = (g & 15) * 24 + b * 12;    // 0..372 within mat
                bf16x8 wv[12];
                #pragma unroll
                for (int q = 0; q < 12; ++q)
                    wv[q] = *(const bf16x8*)(W + (size_t)(rbase + q) * EMB + j * 8);
                #pragma unroll
                for (int q = 0; q < 12; ++q) {
                    float s = bf2f((unsigned short)wv[q][0]) * x8[0]
                            + bf2f((unsigned short)wv[q][1]) * x8[1]
                            + bf2f((unsigned short)wv[q][2]) * x8[2]
                            + bf2f((unsigned short)wv[q][3]) * x8[3]
                            + bf2f((unsigned short)wv[q][4]) * x8[4]
                            + bf2f((unsigned short)wv[q][5]) * x8[5]
                            + bf2f((unsigned short)wv[q][6]) * x8[6]
                            + bf2f((unsigned short)wv[q][7]) * x8[7];
                    s += __shfl_xor(s, 1); s += __shfl_xor(s, 2);
                    s += __shfl_xor(s, 4); s += __shfl_xor(s, 8);
                    if (j == (q & 15)) gg[mat * 384 + rbase + q] = s;
                }
            }
            __syncthreads();

            if (tid < EMB) {
                int e = tid;
                float r_ = sigmoidf_(gg[e] + bui[e] + gg[384 + e] + buh[e]);
                float z_ = sigmoidf_(gg[128 + e] + bui[128 + e] + gg[512 + e] + buh[128 + e]);
                float n_ = tanhf(gg[256 + e] + bui[256 + e] + r_ * (gg[640 + e] + buh[256 + e]));
                NU[(size_t)t * EMB + e] = (1.f - z_) * n_ + z_ * su[e];
            } else if (tid < 2*EMB) {
                int e = tid - EMB;
                float r_ = sigmoidf_(gg[768 + e] + bii[e] + gg[1152 + e] + bih[e]);
                float z_ = sigmoidf_(gg[896 + e] + bii[128 + e] + gg[1280 + e] + bih[128 + e]);
                float n_ = tanhf(gg[1024 + e] + bii[256 + e] + r_ * (gg[1408 + e] + bih[256 + e]));
                NV[(size_t)t * EMB + e] = (1.f - z_) * n_ + z_ * sv[e];
            }
        }
    }
}

// ---------------------------------------------------------------------------
// Kernel 5 (FUSED post): gather+loss -> T1 MFMA -> h1(bf16,LDS) -> T2 MFMA
// -> T3+sigmoid. Block = 64 events, 4 waves.
// ---------------------------------------------------------------------------
__global__ __launch_bounds__(256) void post_fused_kernel(
    const float* __restrict__ U0, const float* __restrict__ V0,
    const int* __restrict__ uids, const int* __restrict__ iids,
    const int* __restrict__ prevu, const int* __restrict__ previ,
    const float* __restrict__ NU, const float* __restrict__ NV,
    const unsigned short* __restrict__ t1wb, const float* __restrict__ T1b,
    const unsigned short* __restrict__ t2wb, const float* __restrict__ T2b,
    const float* __restrict__ T3w, const float* __restrict__ T3b,
    float* __restrict__ out, int nev)
{
    __shared__ __align__(16) unsigned short xau[64][136];
    __shared__ __align__(16) unsigned short xav[64][136];
    __shared__ __align__(16) unsigned short h1b[64][136];
    __shared__ float h2s[64][36];

    int tid = threadIdx.x;
    int ev0 = blockIdx.x * 64;

    // ---- stage (bf16) + loss ----
    #pragma unroll
    for (int rep = 0; rep < 4; ++rep) {
        int idx = rep * 256 + tid;
        int evl = idx >> 4, j16 = idx & 15;
        int t = ev0 + evl;
        float4 a0, a1, c0, c1;
        if (t < nev) {
            int pu = prevu[t], pi = previ[t];
            const float* up = (pu < 0 ? U0 + (size_t)uids[t] * EMB : NU + (size_t)pu * EMB) + j16 * 8;
            const float* vp = (pi < 0 ? V0 + (size_t)iids[t] * EMB : NV + (size_t)pi * EMB) + j16 * 8;
            a0 = ((const float4*)up)[0]; a1 = ((const float4*)up)[1];
            c0 = ((const float4*)vp)[0]; c1 = ((const float4*)vp)[1];
        } else {
            a0 = make_float4(0.f, 0.f, 0.f, 0.f); a1 = a0; c0 = a0; c1 = a0;
        }
        *(ushort4*)&xau[evl][j16 * 8]     = make_ushort4(f2bf(a0.x), f2bf(a0.y), f2bf(a0.z), f2bf(a0.w));
        *(ushort4*)&xau[evl][j16 * 8 + 4] = make_ushort4(f2bf(a1.x), f2bf(a1.y), f2bf(a1.z), f2bf(a1.w));
        *(ushort4*)&xav[evl][j16 * 8]     = make_ushort4(f2bf(c0.x), f2bf(c0.y), f2bf(c0.z), f2bf(c0.w));
        *(ushort4*)&xav[evl][j16 * 8 + 4] = make_ushort4(f2bf(c1.x), f2bf(c1.y), f2bf(c1.z), f2bf(c1.w));
        float dp = a0.x * c0.x + a0.y * c0.y + a0.z * c0.z + a0.w * c0.w
                 + a1.x * c1.x + a1.y * c1.y + a1.z * c1.z + a1.w * c1.w;
        dp += __shfl_xor(dp, 1); dp += __shfl_xor(dp, 2);
        dp += __shfl_xor(dp, 4); dp += __shfl_xor(dp, 8);
        if (j16 == 0 && t < nev)
            out[2 * (size_t)t] = -logf(softplusf_(dp) + 1e-10f);
    }
    __syncthreads();

    int w = tid >> 6, l = tid & 63;
    int lr = l & 15, lk = (l >> 4) * 8;

    // ---- T1: 128 cols, K=256 ([u|v]) ----
    {
        f32x4 acc[8] = {};
        #pragma unroll
        for (int kh = 0; kh < 8; ++kh) {
            const unsigned short* ar = (kh < 4)
                ? &xau[w * 16 + lr][kh * 32 + lk]
                : &xav[w * 16 + lr][(kh - 4) * 32 + lk];
            bf16x8 a = *(const bf16x8*)ar;
            #pragma unroll
            for (int n = 0; n < 8; ++n) {
                bf16x8 b = *(const bf16x8*)(t1wb + (size_t)(n * 16 + lr) * 256 + kh * 32 + lk);
                acc[n] = __builtin_amdgcn_mfma_f32_16x16x32_bf16(a, b, acc[n], 0, 0, 0);
            }
        }
        #pragma unroll
        for (int n = 0; n < 8; ++n) {
            int col = n * 16 + lr;
            float bb = T1b[col];
            #pragma unroll
            for (int i = 0; i < 4; ++i)
                h1b[w * 16 + (l >> 4) * 4 + i][col] = f2bf(fmaxf(acc[n][i] + bb, 0.f));
        }
    }
    __syncthreads();

    // ---- T2: 32 cols, K=128 ----
    {
        f32x4 acc2[2] = {};
        #pragma unroll
        for (int kk = 0; kk < 4; ++kk) {
            bf16x8 a = *(const bf16x8*)&h1b[w * 16 + lr][kk * 32 + lk];
            #pragma unroll
            for (int n = 0; n < 2; ++n) {
                bf16x8 b = *(const bf16x8*)(t2wb + (size_t)(n * 16 + lr) * 128 + kk * 32 + lk);
                acc2[n] = __builtin_amdgcn_mfma_f32_16x16x32_bf16(a, b, acc2[n], 0, 0, 0);
            }
        }
        #pragma unroll
        for (int n = 0; n < 2; ++n) {
            int col = n * 16 + lr;
            float bb = T2b[col];
            #pragma unroll
            for (int i = 0; i < 4; ++i)
                h2s[w * 16 + (l >> 4) * 4 + i][col] = fmaxf(acc2[n][i] + bb, 0.f);
        }
    }
    __syncthreads();

    // ---- T3 + sigmoid ----
    {
        int evl = tid >> 2, q4 = tid & 3;
        float p = 0.f;
        #pragma unroll
        for (int i = 0; i < 8; ++i) {
            int ch = q4 * 8 + i;
            p = fmaf(T3w[ch], h2s[evl][ch], p);
        }
        p += __shfl_xor(p, 1); p += __shfl_xor(p, 2);
        int t = ev0 + evl;
        if (q4 == 0 && t < nev)
            out[2 * (size_t)t + 1] = sigmoidf_(p + T3b[0]);
    }
}

// ---------------------------------------------------------------------------
extern "C" void kernel_launch(void* const* d_in, const int* in_sizes, int n_in,
                              void* d_out, int out_size, void* d_ws, size_t ws_size,
                              hipStream_t stream)
{
    const float* U0  = (const float*)d_in[0];
    const float* V0  = (const float*)d_in[1];
    const float* Wui = (const float*)d_in[2];
    const float* Wuh = (const float*)d_in[3];
    const float* bui = (const float*)d_in[4];
    const float* buh = (const float*)d_in[5];
    const float* Wii = (const float*)d_in[6];
    const float* Wih = (const float*)d_in[7];
    const float* bii = (const float*)d_in[8];
    const float* bih = (const float*)d_in[9];
    const float* T1w = (const float*)d_in[10];
    const float* T1b = (const float*)d_in[11];
    const float* T2w = (const float*)d_in[12];
    const float* T2b = (const float*)d_in[13];
    const float* T3w = (const float*)d_in[14];
    const float* T3b = (const float*)d_in[15];
    const int* uids  = (const int*)d_in[16];
    const int* iids  = (const int*)d_in[17];
    int nev = in_sizes[16];

    char* ws = (char*)d_ws;
    int* base = (int*)ws;
    int* prevu      = base;                 // MAXEV
    int* previ      = base + MAXEV;         // MAXEV
    int* order0     = base + 2 * MAXEV;     // MAXEV
    int* order1     = base + 3 * MAXEV;     // MAXEV
    int* tail2Order = base + 4 * MAXEV;     // MAXEV
    int* compStart  = base + 5 * MAXEV;     // MAXEV+2
    Hdr* hdr        = (Hdr*)(base + 6 * MAXEV + 4);
    float* NU = (float*)(ws + (160 << 10));              // 2 MB
    float* NV = NU + (size_t)MAXEV * EMB;                // 2 MB
    unsigned short* wb_uh = (unsigned short*)(NV + (size_t)MAXEV * EMB);
    unsigned short* wb_ii = wb_uh + 384 * EMB;           // 96 KB each
    unsigned short* wb_ui = wb_ii + 384 * EMB;
    unsigned short* wb_ih = wb_ui + 384 * EMB;
    unsigned short* t1wb  = wb_ih + 384 * EMB;           // 64 KB
    unsigned short* t2wb  = t1wb + EMB * 256;            // 8 KB
    float* out = (float*)d_out;

    prev_kernel<<<MAXEV, 64, 0, stream>>>(
        uids, iids, prevu, previ, nev,
        Wuh, Wii, Wui, Wih, T1w, T2w,
        wb_uh, wb_ii, wb_ui, wb_ih, t1wb, t2wb);
    setup_kernel<<<1, 1024, 0, stream>>>(prevu, previ, order0, order1,
                                         tail2Order, compStart, hdr, nev);

    // Pass A: level-0 events (fused gather + gate MFMA + combine)
    gru_fused_kernel<<<MAXEV / GEV, 256, 0, stream>>>(
        U0, V0, wb_ui, wb_uh, wb_ii, wb_ih, bui, buh, bii, bih,
        uids, iids, prevu, previ, NU, NV, order0, &hdr->nl0, NU, NV);

    // Pass B: level-1 events (preds all level-0, visible by stream order)
    gru_fused_kernel<<<MAXEV / GEV, 256, 0, stream>>>(
        U0, V0, wb_ui, wb_uh, wb_ii, wb_ih, bui, buh, bii, bih,
        uids, iids, prevu, previ, NU, NV, order1, &hdr->nl1, NU, NV);

    // lev>=2 remainder: component-serial (bf16 weights, 2 batches/event)
    tail2_kernel<<<64, 1024, 0, stream>>>(
        U0, V0, wb_ui, wb_uh, bui, buh, wb_ii, wb_ih, bii, bih,
        uids, iids, prevu, previ, tail2Order, compStart, hdr, NU, NV);

    // fused loss + MLP branch
    post_fused_kernel<<<(nev + 63) / 64, 256, 0, stream>>>(
        U0, V0, uids, iids, prevu, previ, NU, NV,
        t1wb, T1b, t2wb, T2b, T3w, T3b, out, nev);
}

// Round 15
// 105.151 us; speedup vs baseline: 1.1090x; 1.0034x over previous
//
#include <hip/hip_runtime.h>
#include <math.h>

#define EMB 128
#define MAXEV 4096
#define GEV 16            // events per fused-GRU block

struct Hdr { int nl0; int nl1; int ncomp2; };

typedef __attribute__((ext_vector_type(8))) short bf16x8;
typedef __attribute__((ext_vector_type(4))) float f32x4;

__device__ __forceinline__ float sigmoidf_(float x) { return 1.0f / (1.0f + expf(-x)); }
__device__ __forceinline__ float softplusf_(float x) {
    return (x > 0.f) ? x + log1pf(expf(-x)) : log1pf(expf(x));
}
__device__ __forceinline__ unsigned short f2bf(float f) {
    unsigned int u = __float_as_uint(f);
    u += 0x7FFFu + ((u >> 16) & 1u);          // round-to-nearest-even
    return (unsigned short)(u >> 16);
}
__device__ __forceinline__ float bf2f(unsigned short s) {
    return __uint_as_float((unsigned int)s << 16);
}

// ---------------------------------------------------------------------------
// Kernel 1 (fused): per-event prev-id search + one-shot weight->bf16 convert.
// ---------------------------------------------------------------------------
__global__ __launch_bounds__(64) void prev_kernel(
    const int* __restrict__ uids, const int* __restrict__ iids,
    int* __restrict__ prevu, int* __restrict__ previ, int nev,
    const float* __restrict__ Wuh, const float* __restrict__ Wii,
    const float* __restrict__ Wui, const float* __restrict__ Wih,
    const float* __restrict__ T1w, const float* __restrict__ T2w,
    unsigned short* __restrict__ wb_uh, unsigned short* __restrict__ wb_ii,
    unsigned short* __restrict__ wb_ui, unsigned short* __restrict__ wb_ih,
    unsigned short* __restrict__ t1wb, unsigned short* __restrict__ t2wb)
{
    int t = blockIdx.x;
    int lane = threadIdx.x;

    {   // weight conversion: 49152 (4x GRU) + 8192 (T1w) + 1024 (T2w) f4
        int gid = t * 64 + lane;
        if (gid < 58368) {
            const float* src; unsigned short* dst; int q;
            if (gid < 49152) {
                int m = gid / 12288; q = gid - m * 12288;
                src = (m == 0) ? Wuh : (m == 1) ? Wii : (m == 2) ? Wui : Wih;
                dst = (m == 0) ? wb_uh : (m == 1) ? wb_ii : (m == 2) ? wb_ui : wb_ih;
            } else if (gid < 57344) { q = gid - 49152; src = T1w; dst = t1wb; }
            else                    { q = gid - 57344; src = T2w; dst = t2wb; }
            float4 v = ((const float4*)src)[q];
            *(ushort4*)(dst + (size_t)q * 4) =
                make_ushort4(f2bf(v.x), f2bf(v.y), f2bf(v.z), f2bf(v.w));
        }
    }

    if (t >= nev) return;
    int myu = uids[t], myi = iids[t];
    int bu = -1, bi = -1;
    for (int j = lane; j < t; j += 64) {
        if (uids[j] == myu) bu = j;
        if (iids[j] == myi) bi = j;
    }
    for (int off = 32; off; off >>= 1) {
        bu = max(bu, __shfl_xor(bu, off));
        bi = max(bi, __shfl_xor(bi, off));
    }
    if (lane == 0) { prevu[t] = bu; previ[t] = bi; }
}

// ---------------------------------------------------------------------------
// Kernel 2 (single block): levels relaxed ONLY over pred-having events
// (~250); components ONLY over the lev>=2 induced subgraph (~15 events).
// ---------------------------------------------------------------------------
__global__ __launch_bounds__(1024) void setup_kernel(
    const int* __restrict__ prevu, const int* __restrict__ previ,
    int* __restrict__ order0, int* __restrict__ order1,
    int* __restrict__ tail2Order, int* __restrict__ compStart,
    Hdr* __restrict__ hdr, int nev)
{
    __shared__ int   lab[MAXEV];
    __shared__ int   tmpT[MAXEV];
    __shared__ int   t2l[MAXEV];
    __shared__ short slev[MAXEV];
    __shared__ int   schanged, sn0, sn1, sn2, sntl;

    int tid = threadIdx.x;
    for (int t = tid; t < nev; t += 1024) slev[t] = 0;
    if (tid == 0) { sn0 = 0; sn1 = 0; sn2 = 0; sntl = 0; }
    __syncthreads();

    for (int t = tid; t < nev; t += 1024) {
        if (prevu[t] >= 0 || previ[t] >= 0) tmpT[atomicAdd(&sntl, 1)] = t;
        else                                 order0[atomicAdd(&sn0, 1)] = t;
    }
    __syncthreads();
    int ntl = sntl;

    for (int it = 0; it < nev; ++it) {
        if (tid == 0) schanged = 0;
        __syncthreads();
        for (int i = tid; i < ntl; i += 1024) {
            int t = tmpT[i];
            int pu = prevu[t], pi = previ[t];
            int nl = 0;
            if (pu >= 0) nl = slev[pu] + 1;
            if (pi >= 0) { int c = slev[pi] + 1; nl = nl > c ? nl : c; }
            if (nl > (int)slev[t]) { slev[t] = (short)nl; schanged = 1; }
        }
        __syncthreads();
        if (!schanged) break;
        __syncthreads();
    }

    for (int i = tid; i < ntl; i += 1024) {
        int t = tmpT[i];
        if (slev[t] == 1)      order1[atomicAdd(&sn1, 1)] = t;
        else if (slev[t] >= 2) t2l[atomicAdd(&sn2, 1)] = t;
    }
    __syncthreads();
    int n2 = sn2;

    for (int i = tid; i < n2; i += 1024) lab[t2l[i]] = t2l[i];
    __syncthreads();
    for (int it = 0; it < nev; ++it) {
        if (tid == 0) schanged = 0;
        __syncthreads();
        for (int i = tid; i < n2; i += 1024) {
            int t = t2l[i];
            int m = lab[t];
            int pu = prevu[t], pi = previ[t];
            bool eu = (pu >= 0 && slev[pu] >= 2);
            bool ei = (pi >= 0 && slev[pi] >= 2);
            if (eu) m = min(m, lab[pu]);
            if (ei) m = min(m, lab[pi]);
            if (m < lab[t]) { atomicMin(&lab[t], m); schanged = 1; }
            if (eu && m < lab[pu]) { atomicMin(&lab[pu], m); schanged = 1; }
            if (ei && m < lab[pi]) { atomicMin(&lab[pi], m); schanged = 1; }
        }
        __syncthreads();
        if (!schanged) break;
        __syncthreads();
    }

    for (int i = tid; i < n2; i += 1024) tmpT[i] = (lab[t2l[i]] << 12) | t2l[i];
    __syncthreads();
    for (int i = tid; i < n2; i += 1024) {
        int k = tmpT[i], r = 0;
        for (int j = 0; j < n2; ++j) r += (tmpT[j] < k);
        tail2Order[r] = k & 0xFFF;
    }
    __syncthreads();

    if (tid == 0) {
        int nc = 0;
        for (int i = 0; i < n2; ++i)
            if (i == 0 || lab[tail2Order[i]] != lab[tail2Order[i - 1]])
                compStart[nc++] = i;
        compStart[nc] = n2;
        hdr->ncomp2 = nc;
        hdr->nl0 = sn0;
        hdr->nl1 = sn1;
    }
}

// ---------------------------------------------------------------------------
// Kernel 3 (both passes, FUSED): gather(+loss) -> gate MFMA -> GRU combine
// -> T1/T2/T3 MFMA score. Block = 16 events, 4 waves. bf16 u,v in LDS
// (stride 136 -> 2-way bank conflict = free). gg pad 772 breaks 768-stride.
// h1/h2 alias the gg buffer (free after combine). NUr/NVr alias NU/NV.
// ---------------------------------------------------------------------------
__global__ __launch_bounds__(256) void gru_fused_kernel(
    const float* __restrict__ U0, const float* __restrict__ V0,
    const unsigned short* __restrict__ wb_ui, const unsigned short* __restrict__ wb_uh,
    const unsigned short* __restrict__ wb_ii, const unsigned short* __restrict__ wb_ih,
    const float* __restrict__ bui, const float* __restrict__ buh,
    const float* __restrict__ bii, const float* __restrict__ bih,
    const unsigned short* __restrict__ t1wb, const float* __restrict__ T1b,
    const unsigned short* __restrict__ t2wb, const float* __restrict__ T2b,
    const float* __restrict__ T3w, const float* __restrict__ T3b,
    const int* __restrict__ uids, const int* __restrict__ iids,
    const int* __restrict__ prevu, const int* __restrict__ previ,
    const float* NUr, const float* NVr,
    const int* __restrict__ order, const int* __restrict__ cnt_p,
    float* NU, float* NV, float* __restrict__ out)
{
    __shared__ __align__(16) unsigned short xbu[GEV][136];
    __shared__ __align__(16) unsigned short xbv[GEV][136];
    __shared__ __align__(16) float gg[GEV][772];
    // MLP scratch aliases gg (free after the GRU phases):
    unsigned short (*h1b)[136] = (unsigned short (*)[136])&gg[0][0];  // 4352 B
    float (*h2s)[36] = (float (*)[36])&gg[2][0];                      // at 6176 B

    int cnt = *cnt_p;
    int e0 = blockIdx.x * GEV;
    if (e0 >= cnt) return;

    int tid = threadIdx.x;
    int ev = tid >> 4, c8 = (tid & 15) * 8;

    {   // stage: 16 threads per event, 8 channels each; loss on the fly
        int e = e0 + ev;
        int t = -1;
        float4 a0, a1, c0, c1;
        if (e < cnt) {
            t = order[e];
            int pu = prevu[t], pi = previ[t];
            const float* up = (pu < 0 ? U0 + (size_t)uids[t] * EMB : NUr + (size_t)pu * EMB) + c8;
            const float* vp = (pi < 0 ? V0 + (size_t)iids[t] * EMB : NVr + (size_t)pi * EMB) + c8;
            a0 = ((const float4*)up)[0]; a1 = ((const float4*)up)[1];
            c0 = ((const float4*)vp)[0]; c1 = ((const float4*)vp)[1];
        } else {
            a0 = make_float4(0.f, 0.f, 0.f, 0.f); a1 = a0; c0 = a0; c1 = a0;
        }
        *(ushort4*)&xbu[ev][c8]     = make_ushort4(f2bf(a0.x), f2bf(a0.y), f2bf(a0.z), f2bf(a0.w));
        *(ushort4*)&xbu[ev][c8 + 4] = make_ushort4(f2bf(a1.x), f2bf(a1.y), f2bf(a1.z), f2bf(a1.w));
        *(ushort4*)&xbv[ev][c8]     = make_ushort4(f2bf(c0.x), f2bf(c0.y), f2bf(c0.z), f2bf(c0.w));
        *(ushort4*)&xbv[ev][c8 + 4] = make_ushort4(f2bf(c1.x), f2bf(c1.y), f2bf(c1.z), f2bf(c1.w));
        float dp = a0.x * c0.x + a0.y * c0.y + a0.z * c0.z + a0.w * c0.w
                 + a1.x * c1.x + a1.y * c1.y + a1.z * c1.z + a1.w * c1.w;
        dp += __shfl_xor(dp, 1); dp += __shfl_xor(dp, 2);
        dp += __shfl_xor(dp, 4); dp += __shfl_xor(dp, 8);
        if ((tid & 15) == 0 && t >= 0)
            out[2 * (size_t)t] = -logf(softplusf_(dp) + 1e-10f);
    }
    __syncthreads();

    int w = tid >> 6, l = tid & 63;
    int lr = l & 15, lk = (l >> 4) * 8;

    for (int ph = 0; ph < 2; ++ph) {
        const unsigned short* Wi = ph ? wb_ii : wb_ui;
        const unsigned short* Wh = ph ? wb_ih : wb_uh;
        const unsigned short (*Xi)[136] = ph ? xbu : xbv;
        const unsigned short (*Xh)[136] = ph ? xbv : xbu;

        f32x4 acc[12] = {};
        #pragma unroll
        for (int kk = 0; kk < 4; ++kk) {
            bf16x8 ai = *(const bf16x8*)&Xi[lr][kk * 32 + lk];
            bf16x8 ah = *(const bf16x8*)&Xh[lr][kk * 32 + lk];
            #pragma unroll
            for (int j = 0; j < 12; ++j) {
                int nt = w * 12 + j;
                bool ish = nt >= 24;
                int brow = (ish ? nt - 24 : nt) * 16 + lr;
                const unsigned short* W = ish ? Wh : Wi;
                bf16x8 b = *(const bf16x8*)(W + (size_t)brow * EMB + kk * 32 + lk);
                acc[j] = __builtin_amdgcn_mfma_f32_16x16x32_bf16(ish ? ah : ai, b, acc[j], 0, 0, 0);
            }
        }
        #pragma unroll
        for (int j = 0; j < 12; ++j) {
            int nt = w * 12 + j;
            #pragma unroll
            for (int i = 0; i < 4; ++i)
                gg[(l >> 4) * 4 + i][nt * 16 + lr] = acc[j][i];
        }
        __syncthreads();

        {   // combine (gg[ev][0..383]=gi, [384..767]=gh)
            int e = e0 + ev;
            if (e < cnt) {
                int t = order[e];
                const float* bi = ph ? bii : bui;
                const float* bh = ph ? bih : buh;
                float* N = ph ? NV : NU;
                const unsigned short (*xh)[136] = ph ? xbv : xbu;
                #pragma unroll
                for (int i = 0; i < 8; ++i) {
                    int ch = c8 + i;
                    float r_ = sigmoidf_(gg[ev][ch] + bi[ch] + gg[ev][384 + ch] + bh[ch]);
                    float z_ = sigmoidf_(gg[ev][128 + ch] + bi[128 + ch] + gg[ev][512 + ch] + bh[128 + ch]);
                    float n_ = tanhf(gg[ev][256 + ch] + bi[256 + ch] + r_ * (gg[ev][640 + ch] + bh[256 + ch]));
                    float h = bf2f(xh[ev][ch]);
                    N[(size_t)t * EMB + ch] = (1.f - z_) * n_ + z_ * h;
                }
            }
        }
        __syncthreads();   // gg reuse (next phase / MLP scratch)
    }

    // ---- T1: 16 ev x 128 cols, K=256 ([u|v]); 4 waves x 2 n-tiles ----
    {
        f32x4 acc1[2] = {};
        #pragma unroll
        for (int kh = 0; kh < 8; ++kh) {
            bf16x8 a = (kh < 4) ? *(const bf16x8*)&xbu[lr][kh * 32 + lk]
                                : *(const bf16x8*)&xbv[lr][(kh - 4) * 32 + lk];
            #pragma unroll
            for (int n = 0; n < 2; ++n) {
                int nt = w * 2 + n;
                bf16x8 b = *(const bf16x8*)(t1wb + (size_t)(nt * 16 + lr) * 256 + kh * 32 + lk);
                acc1[n] = __builtin_amdgcn_mfma_f32_16x16x32_bf16(a, b, acc1[n], 0, 0, 0);
            }
        }
        #pragma unroll
        for (int n = 0; n < 2; ++n) {
            int col = (w * 2 + n) * 16 + lr;
            float bb = T1b[col];
            #pragma unroll
            for (int i = 0; i < 4; ++i)
                h1b[(l >> 4) * 4 + i][col] = f2bf(fmaxf(acc1[n][i] + bb, 0.f));
        }
    }
    __syncthreads();

    // ---- T2: 16 ev x 32 cols, K=128; waves 0,1 ----
    if (w < 2) {
        f32x4 acc2 = {};
        #pragma unroll
        for (int kk = 0; kk < 4; ++kk) {
            bf16x8 a = *(const bf16x8*)&h1b[lr][kk * 32 + lk];
            bf16x8 b = *(const bf16x8*)(t2wb + (size_t)(w * 16 + lr) * 128 + kk * 32 + lk);
            acc2 = __builtin_amdgcn_mfma_f32_16x16x32_bf16(a, b, acc2, 0, 0, 0);
        }
        int col = w * 16 + lr;
        float bb = T2b[col];
        #pragma unroll
        for (int i = 0; i < 4; ++i)
            h2s[(l >> 4) * 4 + i][col] = fmaxf(acc2[i] + bb, 0.f);
    }
    __syncthreads();

    // ---- T3 + sigmoid: 4 lanes/event x 8 channels (wave 0) ----
    if (tid < 64) {
        int evl = tid >> 2, q4 = tid & 3;
        float p = 0.f;
        #pragma unroll
        for (int i = 0; i < 8; ++i) {
            int ch = q4 * 8 + i;
            p = fmaf(T3w[ch], h2s[evl][ch], p);
        }
        p += __shfl_xor(p, 1); p += __shfl_xor(p, 2);
        int e = e0 + evl;
        if (q4 == 0 && e < cnt)
            out[2 * (size_t)order[e] + 1] = sigmoidf_(p + T3b[0]);
    }
}

// ---------------------------------------------------------------------------
// Kernel 4: lev>=2 events (~15), component-serial, 1024 threads; bf16
// weights (2 serial 12-row batches). Fused fp32 loss + MLP epilogue.
// #pragma unroll 1 on the batch loop is LOAD-BEARING (rounds 5/6: full
// unroll -> reg spill -> 100% spill-BW-bound).
// ---------------------------------------------------------------------------
__global__ __launch_bounds__(1024) void tail2_kernel(
    const float* __restrict__ U0,  const float* __restrict__ V0,
    const unsigned short* __restrict__ wb_ui, const unsigned short* __restrict__ wb_uh,
    const float* __restrict__ bui, const float* __restrict__ buh,
    const unsigned short* __restrict__ wb_ii, const unsigned short* __restrict__ wb_ih,
    const float* __restrict__ bii, const float* __restrict__ bih,
    const float* __restrict__ T1w, const float* __restrict__ T1b,
    const float* __restrict__ T2w, const float* __restrict__ T2b,
    const float* __restrict__ T3w, const float* __restrict__ T3b,
    const int* __restrict__ uids,  const int* __restrict__ iids,
    const int* __restrict__ prevu, const int* __restrict__ previ,
    const int* __restrict__ tail2Order, const int* __restrict__ compStart,
    const Hdr* __restrict__ hdr,
    float* __restrict__ NU, float* __restrict__ NV, float* __restrict__ out)
{
    __shared__ __align__(16) float su[EMB];
    __shared__ __align__(16) float sv[EMB];
    __shared__ float gg[1536];
    int tid = threadIdx.x;
    int ncomp = hdr->ncomp2;

    int g = tid >> 4, j = tid & 15;       // 64 groups x 16 lanes
    int mat = g >> 4;                     // 16 groups per matrix
    const unsigned short* W = (mat == 0) ? wb_ui : (mat == 1) ? wb_uh
                            : (mat == 2) ? wb_ii : wb_ih;

    for (int c = blockIdx.x; c < ncomp; c += gridDim.x) {
        int kb = compStart[c], ke = compStart[c + 1];
        for (int k = kb; k < ke; ++k) {
            int t = tail2Order[k];
            int pu = prevu[t], pi = previ[t];
            const float* up = (pu < 0) ? U0 + (size_t)uids[t] * EMB : NU + (size_t)pu * EMB;
            const float* vp = (pi < 0) ? V0 + (size_t)iids[t] * EMB : NV + (size_t)pi * EMB;
            __syncthreads();
            if (tid < EMB)        su[tid] = up[tid];
            else if (tid < 2*EMB) sv[tid - EMB] = vp[tid - EMB];
            __syncthreads();

            const float* x = (mat == 1 || mat == 2) ? su : sv;
            float x8[8];
            #pragma unroll
            for (int i = 0; i < 8; ++i) x8[i] = x[j * 8 + i];

            #pragma unroll 1
            for (int b = 0; b < 2; ++b) {
                int rbase = (g & 15) * 24 + b * 12;    // 0..372 within mat
                bf16x8 wv[12];
                #pragma unroll
                for (int q = 0; q < 12; ++q)
                    wv[q] = *(const bf16x8*)(W + (size_t)(rbase + q) * EMB + j * 8);
                #pragma unroll
                for (int q = 0; q < 12; ++q) {
                    float s = bf2f((unsigned short)wv[q][0]) * x8[0]
                            + bf2f((unsigned short)wv[q][1]) * x8[1]
                            + bf2f((unsigned short)wv[q][2]) * x8[2]
                            + bf2f((unsigned short)wv[q][3]) * x8[3]
                            + bf2f((unsigned short)wv[q][4]) * x8[4]
                            + bf2f((unsigned short)wv[q][5]) * x8[5]
                            + bf2f((unsigned short)wv[q][6]) * x8[6]
                            + bf2f((unsigned short)wv[q][7]) * x8[7];
                    s += __shfl_xor(s, 1); s += __shfl_xor(s, 2);
                    s += __shfl_xor(s, 4); s += __shfl_xor(s, 8);
                    if (j == (q & 15)) gg[mat * 384 + rbase + q] = s;
                }
            }
            __syncthreads();

            if (tid < EMB) {
                int e = tid;
                float r_ = sigmoidf_(gg[e] + bui[e] + gg[384 + e] + buh[e]);
                float z_ = sigmoidf_(gg[128 + e] + bui[128 + e] + gg[512 + e] + buh[128 + e]);
                float n_ = tanhf(gg[256 + e] + bui[256 + e] + r_ * (gg[640 + e] + buh[256 + e]));
                NU[(size_t)t * EMB + e] = (1.f - z_) * n_ + z_ * su[e];
            } else if (tid < 2*EMB) {
                int e = tid - EMB;
                float r_ = sigmoidf_(gg[768 + e] + bii[e] + gg[1152 + e] + bih[e]);
                float z_ = sigmoidf_(gg[896 + e] + bii[128 + e] + gg[1280 + e] + bih[128 + e]);
                float n_ = tanhf(gg[1024 + e] + bii[256 + e] + r_ * (gg[1408 + e] + bih[256 + e]));
                NV[(size_t)t * EMB + e] = (1.f - z_) * n_ + z_ * sv[e];
            }
            __syncthreads();   // gg free; reuse for h1/h2

            // ---- fused post (fp32): loss + T1/T2/T3 ----
            if (tid < 64) {    // loss
                float p = su[tid] * sv[tid] + su[tid + 64] * sv[tid + 64];
                p += __shfl_xor(p, 1);  p += __shfl_xor(p, 2);
                p += __shfl_xor(p, 4);  p += __shfl_xor(p, 8);
                p += __shfl_xor(p, 16); p += __shfl_xor(p, 32);
                if (tid == 0) out[2 * (size_t)t] = -logf(softplusf_(p) + 1e-10f);
            }
            {   // T1: row = tid>>3, 8 lanes x 32 k's
                int r = tid >> 3, kq = tid & 7;
                float s = 0.f;
                #pragma unroll
                for (int kk = 0; kk < 32; ++kk) {
                    int kx = kq * 32 + kk;
                    s = fmaf(T1w[(size_t)r * 256 + kx],
                             (kx < 128) ? su[kx] : sv[kx - 128], s);
                }
                s += __shfl_xor(s, 1); s += __shfl_xor(s, 2); s += __shfl_xor(s, 4);
                if (kq == 0) gg[r] = fmaxf(s + T1b[r], 0.f);
            }
            __syncthreads();
            {   // T2: row = tid>>5, 32 lanes x 4 k's
                int r2 = tid >> 5, kq = tid & 31;
                float s = 0.f;
                #pragma unroll
                for (int kk = 0; kk < 4; ++kk)
                    s = fmaf(T2w[(size_t)r2 * 128 + kq * 4 + kk], gg[kq * 4 + kk], s);
                s += __shfl_xor(s, 1); s += __shfl_xor(s, 2);
                s += __shfl_xor(s, 4); s += __shfl_xor(s, 8); s += __shfl_xor(s, 16);
                if (kq == 0) gg[200 + r2] = fmaxf(s + T2b[r2], 0.f);
            }
            __syncthreads();
            if (tid < 32) {    // T3
                float p = T3w[tid] * gg[200 + tid];
                p += __shfl_xor(p, 1); p += __shfl_xor(p, 2);
                p += __shfl_xor(p, 4); p += __shfl_xor(p, 8); p += __shfl_xor(p, 16);
                if (tid == 0) out[2 * (size_t)t + 1] = sigmoidf_(p + T3b[0]);
            }
        }
    }
}

// ---------------------------------------------------------------------------
extern "C" void kernel_launch(void* const* d_in, const int* in_sizes, int n_in,
                              void* d_out, int out_size, void* d_ws, size_t ws_size,
                              hipStream_t stream)
{
    const float* U0  = (const float*)d_in[0];
    const float* V0  = (const float*)d_in[1];
    const float* Wui = (const float*)d_in[2];
    const float* Wuh = (const float*)d_in[3];
    const float* bui = (const float*)d_in[4];
    const float* buh = (const float*)d_in[5];
    const float* Wii = (const float*)d_in[6];
    const float* Wih = (const float*)d_in[7];
    const float* bii = (const float*)d_in[8];
    const float* bih = (const float*)d_in[9];
    const float* T1w = (const float*)d_in[10];
    const float* T1b = (const float*)d_in[11];
    const float* T2w = (const float*)d_in[12];
    const float* T2b = (const float*)d_in[13];
    const float* T3w = (const float*)d_in[14];
    const float* T3b = (const float*)d_in[15];
    const int* uids  = (const int*)d_in[16];
    const int* iids  = (const int*)d_in[17];
    int nev = in_sizes[16];

    char* ws = (char*)d_ws;
    int* base = (int*)ws;
    int* prevu      = base;                 // MAXEV
    int* previ      = base + MAXEV;         // MAXEV
    int* order0     = base + 2 * MAXEV;     // MAXEV
    int* order1     = base + 3 * MAXEV;     // MAXEV
    int* tail2Order = base + 4 * MAXEV;     // MAXEV
    int* compStart  = base + 5 * MAXEV;     // MAXEV+2
    Hdr* hdr        = (Hdr*)(base + 6 * MAXEV + 4);
    float* NU = (float*)(ws + (160 << 10));              // 2 MB
    float* NV = NU + (size_t)MAXEV * EMB;                // 2 MB
    unsigned short* wb_uh = (unsigned short*)(NV + (size_t)MAXEV * EMB);
    unsigned short* wb_ii = wb_uh + 384 * EMB;           // 96 KB each
    unsigned short* wb_ui = wb_ii + 384 * EMB;
    unsigned short* wb_ih = wb_ui + 384 * EMB;
    unsigned short* t1wb  = wb_ih + 384 * EMB;           // 64 KB
    unsigned short* t2wb  = t1wb + EMB * 256;            // 8 KB
    float* out = (float*)d_out;

    prev_kernel<<<MAXEV, 64, 0, stream>>>(
        uids, iids, prevu, previ, nev,
        Wuh, Wii, Wui, Wih, T1w, T2w,
        wb_uh, wb_ii, wb_ui, wb_ih, t1wb, t2wb);
    setup_kernel<<<1, 1024, 0, stream>>>(prevu, previ, order0, order1,
                                         tail2Order, compStart, hdr, nev);

    // Pass A: level-0 events (gather + loss + gate MFMA + combine + score)
    gru_fused_kernel<<<MAXEV / GEV, 256, 0, stream>>>(
        U0, V0, wb_ui, wb_uh, wb_ii, wb_ih, bui, buh, bii, bih,
        t1wb, T1b, t2wb, T2b, T3w, T3b,
        uids, iids, prevu, previ, NU, NV, order0, &hdr->nl0, NU, NV, out);

    // Pass B: level-1 events
    gru_fused_kernel<<<MAXEV / GEV, 256, 0, stream>>>(
        U0, V0, wb_ui, wb_uh, wb_ii, wb_ih, bui, buh, bii, bih,
        t1wb, T1b, t2wb, T2b, T3w, T3b,
        uids, iids, prevu, previ, NU, NV, order1, &hdr->nl1, NU, NV, out);

    // lev>=2 remainder: component-serial, fused post epilogue
    tail2_kernel<<<64, 1024, 0, stream>>>(
        U0, V0, wb_ui, wb_uh, bui, buh, wb_ii, wb_ih, bii, bih,
        T1w, T1b, T2w, T2b, T3w, T3b,
        uids, iids, prevu, previ, tail2Order, compStart, hdr, NU, NV, out);
}

// Round 16
// 101.691 us; speedup vs baseline: 1.1468x; 1.0340x over previous
//
#include <hip/hip_runtime.h>
#include <math.h>

#define EMB 128
#define MAXEV 4096
#define GEV 16            // events per fused-GRU block

struct Hdr { int nl0; int nl1; int ncomp2; };

typedef __attribute__((ext_vector_type(8))) short bf16x8;
typedef __attribute__((ext_vector_type(4))) float f32x4;

__device__ __forceinline__ float sigmoidf_(float x) { return 1.0f / (1.0f + expf(-x)); }
__device__ __forceinline__ float softplusf_(float x) {
    return (x > 0.f) ? x + log1pf(expf(-x)) : log1pf(expf(x));
}
__device__ __forceinline__ unsigned short f2bf(float f) {
    unsigned int u = __float_as_uint(f);
    u += 0x7FFFu + ((u >> 16) & 1u);          // round-to-nearest-even
    return (unsigned short)(u >> 16);
}
__device__ __forceinline__ float bf2f(unsigned short s) {
    return __uint_as_float((unsigned int)s << 16);
}

// ---------------------------------------------------------------------------
// Kernel 1 (fused): per-event prev-id search + one-shot weight->bf16 convert.
// ---------------------------------------------------------------------------
__global__ __launch_bounds__(64) void prev_kernel(
    const int* __restrict__ uids, const int* __restrict__ iids,
    int* __restrict__ prevu, int* __restrict__ previ, int nev,
    const float* __restrict__ Wuh, const float* __restrict__ Wii,
    const float* __restrict__ Wui, const float* __restrict__ Wih,
    const float* __restrict__ T1w, const float* __restrict__ T2w,
    unsigned short* __restrict__ wb_uh, unsigned short* __restrict__ wb_ii,
    unsigned short* __restrict__ wb_ui, unsigned short* __restrict__ wb_ih,
    unsigned short* __restrict__ t1wb, unsigned short* __restrict__ t2wb)
{
    int t = blockIdx.x;
    int lane = threadIdx.x;

    {   // weight conversion: 49152 (4x GRU) + 8192 (T1w) + 1024 (T2w) f4
        int gid = t * 64 + lane;
        if (gid < 58368) {
            const float* src; unsigned short* dst; int q;
            if (gid < 49152) {
                int m = gid / 12288; q = gid - m * 12288;
                src = (m == 0) ? Wuh : (m == 1) ? Wii : (m == 2) ? Wui : Wih;
                dst = (m == 0) ? wb_uh : (m == 1) ? wb_ii : (m == 2) ? wb_ui : wb_ih;
            } else if (gid < 57344) { q = gid - 49152; src = T1w; dst = t1wb; }
            else                    { q = gid - 57344; src = T2w; dst = t2wb; }
            float4 v = ((const float4*)src)[q];
            *(ushort4*)(dst + (size_t)q * 4) =
                make_ushort4(f2bf(v.x), f2bf(v.y), f2bf(v.z), f2bf(v.w));
        }
    }

    if (t >= nev) return;
    int myu = uids[t], myi = iids[t];
    int bu = -1, bi = -1;
    for (int j = lane; j < t; j += 64) {
        if (uids[j] == myu) bu = j;
        if (iids[j] == myi) bi = j;
    }
    for (int off = 32; off; off >>= 1) {
        bu = max(bu, __shfl_xor(bu, off));
        bi = max(bi, __shfl_xor(bi, off));
    }
    if (lane == 0) { prevu[t] = bu; previ[t] = bi; }
}

// ---------------------------------------------------------------------------
// Kernel 2 (single block): levels relaxed ONLY over pred-having events
// (~250); components ONLY over the lev>=2 induced subgraph (~15 events).
// ---------------------------------------------------------------------------
__global__ __launch_bounds__(1024) void setup_kernel(
    const int* __restrict__ prevu, const int* __restrict__ previ,
    int* __restrict__ order0, int* __restrict__ order1,
    int* __restrict__ tail2Order, int* __restrict__ compStart,
    Hdr* __restrict__ hdr, int nev)
{
    __shared__ int   lab[MAXEV];
    __shared__ int   tmpT[MAXEV];
    __shared__ int   t2l[MAXEV];
    __shared__ short slev[MAXEV];
    __shared__ int   schanged, sn0, sn1, sn2, sntl;

    int tid = threadIdx.x;
    for (int t = tid; t < nev; t += 1024) slev[t] = 0;
    if (tid == 0) { sn0 = 0; sn1 = 0; sn2 = 0; sntl = 0; }
    __syncthreads();

    for (int t = tid; t < nev; t += 1024) {
        if (prevu[t] >= 0 || previ[t] >= 0) tmpT[atomicAdd(&sntl, 1)] = t;
        else                                 order0[atomicAdd(&sn0, 1)] = t;
    }
    __syncthreads();
    int ntl = sntl;

    for (int it = 0; it < nev; ++it) {
        if (tid == 0) schanged = 0;
        __syncthreads();
        for (int i = tid; i < ntl; i += 1024) {
            int t = tmpT[i];
            int pu = prevu[t], pi = previ[t];
            int nl = 0;
            if (pu >= 0) nl = slev[pu] + 1;
            if (pi >= 0) { int c = slev[pi] + 1; nl = nl > c ? nl : c; }
            if (nl > (int)slev[t]) { slev[t] = (short)nl; schanged = 1; }
        }
        __syncthreads();
        if (!schanged) break;
        __syncthreads();
    }

    for (int i = tid; i < ntl; i += 1024) {
        int t = tmpT[i];
        if (slev[t] == 1)      order1[atomicAdd(&sn1, 1)] = t;
        else if (slev[t] >= 2) t2l[atomicAdd(&sn2, 1)] = t;
    }
    __syncthreads();
    int n2 = sn2;

    for (int i = tid; i < n2; i += 1024) lab[t2l[i]] = t2l[i];
    __syncthreads();
    for (int it = 0; it < nev; ++it) {
        if (tid == 0) schanged = 0;
        __syncthreads();
        for (int i = tid; i < n2; i += 1024) {
            int t = t2l[i];
            int m = lab[t];
            int pu = prevu[t], pi = previ[t];
            bool eu = (pu >= 0 && slev[pu] >= 2);
            bool ei = (pi >= 0 && slev[pi] >= 2);
            if (eu) m = min(m, lab[pu]);
            if (ei) m = min(m, lab[pi]);
            if (m < lab[t]) { atomicMin(&lab[t], m); schanged = 1; }
            if (eu && m < lab[pu]) { atomicMin(&lab[pu], m); schanged = 1; }
            if (ei && m < lab[pi]) { atomicMin(&lab[pi], m); schanged = 1; }
        }
        __syncthreads();
        if (!schanged) break;
        __syncthreads();
    }

    for (int i = tid; i < n2; i += 1024) tmpT[i] = (lab[t2l[i]] << 12) | t2l[i];
    __syncthreads();
    for (int i = tid; i < n2; i += 1024) {
        int k = tmpT[i], r = 0;
        for (int j = 0; j < n2; ++j) r += (tmpT[j] < k);
        tail2Order[r] = k & 0xFFF;
    }
    __syncthreads();

    if (tid == 0) {
        int nc = 0;
        for (int i = 0; i < n2; ++i)
            if (i == 0 || lab[tail2Order[i]] != lab[tail2Order[i - 1]])
                compStart[nc++] = i;
        compStart[nc] = n2;
        hdr->ncomp2 = nc;
        hdr->nl0 = sn0;
        hdr->nl1 = sn1;
    }
}

// ---------------------------------------------------------------------------
// Kernel 3 (both passes, FUSED): gather(+loss) -> gate MFMA -> GRU combine
// -> T1/T2/T3 MFMA score. Block = 16 events, 4 waves. bf16 u,v in LDS
// (stride 136 -> 2-way bank conflict = free). gg pad 772 breaks 768-stride.
// h1/h2 alias the gg buffer (free after combine). NUr/NVr alias NU/NV.
// ---------------------------------------------------------------------------
__global__ __launch_bounds__(256) void gru_fused_kernel(
    const float* __restrict__ U0, const float* __restrict__ V0,
    const unsigned short* __restrict__ wb_ui, const unsigned short* __restrict__ wb_uh,
    const unsigned short* __restrict__ wb_ii, const unsigned short* __restrict__ wb_ih,
    const float* __restrict__ bui, const float* __restrict__ buh,
    const float* __restrict__ bii, const float* __restrict__ bih,
    const unsigned short* __restrict__ t1wb, const float* __restrict__ T1b,
    const unsigned short* __restrict__ t2wb, const float* __restrict__ T2b,
    const float* __restrict__ T3w, const float* __restrict__ T3b,
    const int* __restrict__ uids, const int* __restrict__ iids,
    const int* __restrict__ prevu, const int* __restrict__ previ,
    const float* NUr, const float* NVr,
    const int* __restrict__ order, const int* __restrict__ cnt_p,
    float* NU, float* NV, float* __restrict__ out)
{
    __shared__ __align__(16) unsigned short xbu[GEV][136];
    __shared__ __align__(16) unsigned short xbv[GEV][136];
    __shared__ __align__(16) float gg[GEV][772];
    unsigned short (*h1b)[136] = (unsigned short (*)[136])&gg[0][0];
    float (*h2s)[36] = (float (*)[36])&gg[2][0];

    int cnt = *cnt_p;
    int e0 = blockIdx.x * GEV;
    if (e0 >= cnt) return;

    int tid = threadIdx.x;
    int ev = tid >> 4, c8 = (tid & 15) * 8;

    {   // stage: 16 threads per event, 8 channels each; loss on the fly
        int e = e0 + ev;
        int t = -1;
        float4 a0, a1, c0, c1;
        if (e < cnt) {
            t = order[e];
            int pu = prevu[t], pi = previ[t];
            const float* up = (pu < 0 ? U0 + (size_t)uids[t] * EMB : NUr + (size_t)pu * EMB) + c8;
            const float* vp = (pi < 0 ? V0 + (size_t)iids[t] * EMB : NVr + (size_t)pi * EMB) + c8;
            a0 = ((const float4*)up)[0]; a1 = ((const float4*)up)[1];
            c0 = ((const float4*)vp)[0]; c1 = ((const float4*)vp)[1];
        } else {
            a0 = make_float4(0.f, 0.f, 0.f, 0.f); a1 = a0; c0 = a0; c1 = a0;
        }
        *(ushort4*)&xbu[ev][c8]     = make_ushort4(f2bf(a0.x), f2bf(a0.y), f2bf(a0.z), f2bf(a0.w));
        *(ushort4*)&xbu[ev][c8 + 4] = make_ushort4(f2bf(a1.x), f2bf(a1.y), f2bf(a1.z), f2bf(a1.w));
        *(ushort4*)&xbv[ev][c8]     = make_ushort4(f2bf(c0.x), f2bf(c0.y), f2bf(c0.z), f2bf(c0.w));
        *(ushort4*)&xbv[ev][c8 + 4] = make_ushort4(f2bf(c1.x), f2bf(c1.y), f2bf(c1.z), f2bf(c1.w));
        float dp = a0.x * c0.x + a0.y * c0.y + a0.z * c0.z + a0.w * c0.w
                 + a1.x * c1.x + a1.y * c1.y + a1.z * c1.z + a1.w * c1.w;
        dp += __shfl_xor(dp, 1); dp += __shfl_xor(dp, 2);
        dp += __shfl_xor(dp, 4); dp += __shfl_xor(dp, 8);
        if ((tid & 15) == 0 && t >= 0)
            out[2 * (size_t)t] = -logf(softplusf_(dp) + 1e-10f);
    }
    __syncthreads();

    int w = tid >> 6, l = tid & 63;
    int lr = l & 15, lk = (l >> 4) * 8;

    for (int ph = 0; ph < 2; ++ph) {
        const unsigned short* Wi = ph ? wb_ii : wb_ui;
        const unsigned short* Wh = ph ? wb_ih : wb_uh;
        const unsigned short (*Xi)[136] = ph ? xbu : xbv;
        const unsigned short (*Xh)[136] = ph ? xbv : xbu;

        f32x4 acc[12] = {};
        #pragma unroll
        for (int kk = 0; kk < 4; ++kk) {
            bf16x8 ai = *(const bf16x8*)&Xi[lr][kk * 32 + lk];
            bf16x8 ah = *(const bf16x8*)&Xh[lr][kk * 32 + lk];
            #pragma unroll
            for (int j = 0; j < 12; ++j) {
                int nt = w * 12 + j;
                bool ish = nt >= 24;
                int brow = (ish ? nt - 24 : nt) * 16 + lr;
                const unsigned short* W = ish ? Wh : Wi;
                bf16x8 b = *(const bf16x8*)(W + (size_t)brow * EMB + kk * 32 + lk);
                acc[j] = __builtin_amdgcn_mfma_f32_16x16x32_bf16(ish ? ah : ai, b, acc[j], 0, 0, 0);
            }
        }
        #pragma unroll
        for (int j = 0; j < 12; ++j) {
            int nt = w * 12 + j;
            #pragma unroll
            for (int i = 0; i < 4; ++i)
                gg[(l >> 4) * 4 + i][nt * 16 + lr] = acc[j][i];
        }
        __syncthreads();

        {   // combine (gg[ev][0..383]=gi, [384..767]=gh)
            int e = e0 + ev;
            if (e < cnt) {
                int t = order[e];
                const float* bi = ph ? bii : bui;
                const float* bh = ph ? bih : buh;
                float* N = ph ? NV : NU;
                const unsigned short (*xh)[136] = ph ? xbv : xbu;
                #pragma unroll
                for (int i = 0; i < 8; ++i) {
                    int ch = c8 + i;
                    float r_ = sigmoidf_(gg[ev][ch] + bi[ch] + gg[ev][384 + ch] + bh[ch]);
                    float z_ = sigmoidf_(gg[ev][128 + ch] + bi[128 + ch] + gg[ev][512 + ch] + bh[128 + ch]);
                    float n_ = tanhf(gg[ev][256 + ch] + bi[256 + ch] + r_ * (gg[ev][640 + ch] + bh[256 + ch]));
                    float h = bf2f(xh[ev][ch]);
                    N[(size_t)t * EMB + ch] = (1.f - z_) * n_ + z_ * h;
                }
            }
        }
        __syncthreads();
    }

    // ---- T1: 16 ev x 128 cols, K=256 ([u|v]); 4 waves x 2 n-tiles ----
    {
        f32x4 acc1[2] = {};
        #pragma unroll
        for (int kh = 0; kh < 8; ++kh) {
            bf16x8 a = (kh < 4) ? *(const bf16x8*)&xbu[lr][kh * 32 + lk]
                                : *(const bf16x8*)&xbv[lr][(kh - 4) * 32 + lk];
            #pragma unroll
            for (int n = 0; n < 2; ++n) {
                int nt = w * 2 + n;
                bf16x8 b = *(const bf16x8*)(t1wb + (size_t)(nt * 16 + lr) * 256 + kh * 32 + lk);
                acc1[n] = __builtin_amdgcn_mfma_f32_16x16x32_bf16(a, b, acc1[n], 0, 0, 0);
            }
        }
        #pragma unroll
        for (int n = 0; n < 2; ++n) {
            int col = (w * 2 + n) * 16 + lr;
            float bb = T1b[col];
            #pragma unroll
            for (int i = 0; i < 4; ++i)
                h1b[(l >> 4) * 4 + i][col] = f2bf(fmaxf(acc1[n][i] + bb, 0.f));
        }
    }
    __syncthreads();

    // ---- T2: 16 ev x 32 cols, K=128; waves 0,1 ----
    if (w < 2) {
        f32x4 acc2 = {};
        #pragma unroll
        for (int kk = 0; kk < 4; ++kk) {
            bf16x8 a = *(const bf16x8*)&h1b[lr][kk * 32 + lk];
            bf16x8 b = *(const bf16x8*)(t2wb + (size_t)(w * 16 + lr) * 128 + kk * 32 + lk);
            acc2 = __builtin_amdgcn_mfma_f32_16x16x32_bf16(a, b, acc2, 0, 0, 0);
        }
        int col = w * 16 + lr;
        float bb = T2b[col];
        #pragma unroll
        for (int i = 0; i < 4; ++i)
            h2s[(l >> 4) * 4 + i][col] = fmaxf(acc2[i] + bb, 0.f);
    }
    __syncthreads();

    // ---- T3 + sigmoid: 4 lanes/event x 8 channels (wave 0) ----
    if (tid < 64) {
        int evl = tid >> 2, q4 = tid & 3;
        float p = 0.f;
        #pragma unroll
        for (int i = 0; i < 8; ++i) {
            int ch = q4 * 8 + i;
            p = fmaf(T3w[ch], h2s[evl][ch], p);
        }
        p += __shfl_xor(p, 1); p += __shfl_xor(p, 2);
        int e = e0 + evl;
        if (q4 == 0 && e < cnt)
            out[2 * (size_t)order[e] + 1] = sigmoidf_(p + T3b[0]);
    }
}

// ---------------------------------------------------------------------------
// Kernel 4: lev>=2 events (~15), component-serial, 1024 threads; bf16
// weights (2 serial 12-row batches). Fused loss + MLP epilogue.
// T1 epilogue uses bf16 t1wb with bf16x8 VECTOR loads: round-15 fp32 scalar
// version had 64-distinct-lines-per-instruction gather (128 KB/event) that
// serialized the lone CU's TA port -> 39.7us kernel. #pragma unroll 1 on
// the batch loop is LOAD-BEARING (rounds 5/6: full unroll -> reg spill).
// ---------------------------------------------------------------------------
__global__ __launch_bounds__(1024) void tail2_kernel(
    const float* __restrict__ U0,  const float* __restrict__ V0,
    const unsigned short* __restrict__ wb_ui, const unsigned short* __restrict__ wb_uh,
    const float* __restrict__ bui, const float* __restrict__ buh,
    const unsigned short* __restrict__ wb_ii, const unsigned short* __restrict__ wb_ih,
    const float* __restrict__ bii, const float* __restrict__ bih,
    const unsigned short* __restrict__ t1wb, const float* __restrict__ T1b,
    const float* __restrict__ T2w, const float* __restrict__ T2b,
    const float* __restrict__ T3w, const float* __restrict__ T3b,
    const int* __restrict__ uids,  const int* __restrict__ iids,
    const int* __restrict__ prevu, const int* __restrict__ previ,
    const int* __restrict__ tail2Order, const int* __restrict__ compStart,
    const Hdr* __restrict__ hdr,
    float* __restrict__ NU, float* __restrict__ NV, float* __restrict__ out)
{
    __shared__ __align__(16) float su[EMB];
    __shared__ __align__(16) float sv[EMB];
    __shared__ float gg[1536];
    int tid = threadIdx.x;
    int ncomp = hdr->ncomp2;

    int g = tid >> 4, j = tid & 15;       // 64 groups x 16 lanes
    int mat = g >> 4;                     // 16 groups per matrix
    const unsigned short* W = (mat == 0) ? wb_ui : (mat == 1) ? wb_uh
                            : (mat == 2) ? wb_ii : wb_ih;

    for (int c = blockIdx.x; c < ncomp; c += gridDim.x) {
        int kb = compStart[c], ke = compStart[c + 1];
        for (int k = kb; k < ke; ++k) {
            int t = tail2Order[k];
            int pu = prevu[t], pi = previ[t];
            const float* up = (pu < 0) ? U0 + (size_t)uids[t] * EMB : NU + (size_t)pu * EMB;
            const float* vp = (pi < 0) ? V0 + (size_t)iids[t] * EMB : NV + (size_t)pi * EMB;
            __syncthreads();
            if (tid < EMB)        su[tid] = up[tid];
            else if (tid < 2*EMB) sv[tid - EMB] = vp[tid - EMB];
            __syncthreads();

            const float* x = (mat == 1 || mat == 2) ? su : sv;
            float x8[8];
            #pragma unroll
            for (int i = 0; i < 8; ++i) x8[i] = x[j * 8 + i];

            #pragma unroll 1
            for (int b = 0; b < 2; ++b) {
                int rbase = (g & 15) * 24 + b * 12;    // 0..372 within mat
                bf16x8 wv[12];
                #pragma unroll
                for (int q = 0; q < 12; ++q)
                    wv[q] = *(const bf16x8*)(W + (size_t)(rbase + q) * EMB + j * 8);
                #pragma unroll
                for (int q = 0; q < 12; ++q) {
                    float s = bf2f((unsigned short)wv[q][0]) * x8[0]
                            + bf2f((unsigned short)wv[q][1]) * x8[1]
                            + bf2f((unsigned short)wv[q][2]) * x8[2]
                            + bf2f((unsigned short)wv[q][3]) * x8[3]
                            + bf2f((unsigned short)wv[q][4]) * x8[4]
                            + bf2f((unsigned short)wv[q][5]) * x8[5]
                            + bf2f((unsigned short)wv[q][6]) * x8[6]
                            + bf2f((unsigned short)wv[q][7]) * x8[7];
                    s += __shfl_xor(s, 1); s += __shfl_xor(s, 2);
                    s += __shfl_xor(s, 4); s += __shfl_xor(s, 8);
                    if (j == (q & 15)) gg[mat * 384 + rbase + q] = s;
                }
            }
            __syncthreads();

            if (tid < EMB) {
                int e = tid;
                float r_ = sigmoidf_(gg[e] + bui[e] + gg[384 + e] + buh[e]);
                float z_ = sigmoidf_(gg[128 + e] + bui[128 + e] + gg[512 + e] + buh[128 + e]);
                float n_ = tanhf(gg[256 + e] + bui[256 + e] + r_ * (gg[640 + e] + buh[256 + e]));
                NU[(size_t)t * EMB + e] = (1.f - z_) * n_ + z_ * su[e];
            } else if (tid < 2*EMB) {
                int e = tid - EMB;
                float r_ = sigmoidf_(gg[768 + e] + bii[e] + gg[1152 + e] + bih[e]);
                float z_ = sigmoidf_(gg[896 + e] + bii[128 + e] + gg[1280 + e] + bih[128 + e]);
                float n_ = tanhf(gg[1024 + e] + bii[256 + e] + r_ * (gg[1408 + e] + bih[256 + e]));
                NV[(size_t)t * EMB + e] = (1.f - z_) * n_ + z_ * sv[e];
            }
            __syncthreads();   // gg free; reuse for h1/h2

            // ---- fused post: loss + T1(bf16, vectorized) + T2(f4) + T3 ----
            if (tid < 64) {    // loss (fp32)
                float p = su[tid] * sv[tid] + su[tid + 64] * sv[tid + 64];
                p += __shfl_xor(p, 1);  p += __shfl_xor(p, 2);
                p += __shfl_xor(p, 4);  p += __shfl_xor(p, 8);
                p += __shfl_xor(p, 16); p += __shfl_xor(p, 32);
                if (tid == 0) out[2 * (size_t)t] = -logf(softplusf_(p) + 1e-10f);
            }
            {   // T1: row = tid>>3 (128 rows), 8 lanes x 4 bf16x8 loads
                int r = tid >> 3, kq = tid & 7;
                const float* xx = (kq < 4) ? su : sv;
                int off = (kq < 4) ? 0 : 128;
                float s = 0.f;
                #pragma unroll
                for (int m = 0; m < 4; ++m) {
                    bf16x8 wv = *(const bf16x8*)(t1wb + (size_t)r * 256 + kq * 32 + m * 8);
                    #pragma unroll
                    for (int i = 0; i < 8; ++i)
                        s = fmaf(bf2f((unsigned short)wv[i]),
                                 xx[kq * 32 + m * 8 + i - off], s);
                }
                s += __shfl_xor(s, 1); s += __shfl_xor(s, 2); s += __shfl_xor(s, 4);
                if (kq == 0) gg[r] = fmaxf(s + T1b[r], 0.f);
            }
            __syncthreads();
            {   // T2: row = tid>>5, 32 lanes x one float4 each
                int r2 = tid >> 5, kq = tid & 31;
                float4 wv = *(const float4*)(T2w + (size_t)r2 * 128 + kq * 4);
                float s = wv.x * gg[kq * 4]     + wv.y * gg[kq * 4 + 1]
                        + wv.z * gg[kq * 4 + 2] + wv.w * gg[kq * 4 + 3];
                s += __shfl_xor(s, 1); s += __shfl_xor(s, 2);
                s += __shfl_xor(s, 4); s += __shfl_xor(s, 8); s += __shfl_xor(s, 16);
                if (kq == 0) gg[200 + r2] = fmaxf(s + T2b[r2], 0.f);
            }
            __syncthreads();
            if (tid < 32) {    // T3
                float p = T3w[tid] * gg[200 + tid];
                p += __shfl_xor(p, 1); p += __shfl_xor(p, 2);
                p += __shfl_xor(p, 4); p += __shfl_xor(p, 8); p += __shfl_xor(p, 16);
                if (tid == 0) out[2 * (size_t)t + 1] = sigmoidf_(p + T3b[0]);
            }
        }
    }
}

// ---------------------------------------------------------------------------
extern "C" void kernel_launch(void* const* d_in, const int* in_sizes, int n_in,
                              void* d_out, int out_size, void* d_ws, size_t ws_size,
                              hipStream_t stream)
{
    const float* U0  = (const float*)d_in[0];
    const float* V0  = (const float*)d_in[1];
    const float* Wui = (const float*)d_in[2];
    const float* Wuh = (const float*)d_in[3];
    const float* bui = (const float*)d_in[4];
    const float* buh = (const float*)d_in[5];
    const float* Wii = (const float*)d_in[6];
    const float* Wih = (const float*)d_in[7];
    const float* bii = (const float*)d_in[8];
    const float* bih = (const float*)d_in[9];
    const float* T1w = (const float*)d_in[10];
    const float* T1b = (const float*)d_in[11];
    const float* T2w = (const float*)d_in[12];
    const float* T2b = (const float*)d_in[13];
    const float* T3w = (const float*)d_in[14];
    const float* T3b = (const float*)d_in[15];
    const int* uids  = (const int*)d_in[16];
    const int* iids  = (const int*)d_in[17];
    int nev = in_sizes[16];

    char* ws = (char*)d_ws;
    int* base = (int*)ws;
    int* prevu      = base;                 // MAXEV
    int* previ      = base + MAXEV;         // MAXEV
    int* order0     = base + 2 * MAXEV;     // MAXEV
    int* order1     = base + 3 * MAXEV;     // MAXEV
    int* tail2Order = base + 4 * MAXEV;     // MAXEV
    int* compStart  = base + 5 * MAXEV;     // MAXEV+2
    Hdr* hdr        = (Hdr*)(base + 6 * MAXEV + 4);
    float* NU = (float*)(ws + (160 << 10));              // 2 MB
    float* NV = NU + (size_t)MAXEV * EMB;                // 2 MB
    unsigned short* wb_uh = (unsigned short*)(NV + (size_t)MAXEV * EMB);
    unsigned short* wb_ii = wb_uh + 384 * EMB;           // 96 KB each
    unsigned short* wb_ui = wb_ii + 384 * EMB;
    unsigned short* wb_ih = wb_ui + 384 * EMB;
    unsigned short* t1wb  = wb_ih + 384 * EMB;           // 64 KB
    unsigned short* t2wb  = t1wb + EMB * 256;            // 8 KB
    float* out = (float*)d_out;

    prev_kernel<<<MAXEV, 64, 0, stream>>>(
        uids, iids, prevu, previ, nev,
        Wuh, Wii, Wui, Wih, T1w, T2w,
        wb_uh, wb_ii, wb_ui, wb_ih, t1wb, t2wb);
    setup_kernel<<<1, 1024, 0, stream>>>(prevu, previ, order0, order1,
                                         tail2Order, compStart, hdr, nev);

    // Pass A: level-0 events (gather + loss + gate MFMA + combine + score)
    gru_fused_kernel<<<MAXEV / GEV, 256, 0, stream>>>(
        U0, V0, wb_ui, wb_uh, wb_ii, wb_ih, bui, buh, bii, bih,
        t1wb, T1b, t2wb, T2b, T3w, T3b,
        uids, iids, prevu, previ, NU, NV, order0, &hdr->nl0, NU, NV, out);

    // Pass B: level-1 events
    gru_fused_kernel<<<MAXEV / GEV, 256, 0, stream>>>(
        U0, V0, wb_ui, wb_uh, wb_ii, wb_ih, bui, buh, bii, bih,
        t1wb, T1b, t2wb, T2b, T3w, T3b,
        uids, iids, prevu, previ, NU, NV, order1, &hdr->nl1, NU, NV, out);

    // lev>=2 remainder: component-serial, fused post epilogue
    tail2_kernel<<<64, 1024, 0, stream>>>(
        U0, V0, wb_ui, wb_uh, bui, buh, wb_ii, wb_ih, bii, bih,
        t1wb, T1b, T2w, T2b, T3w, T3b,
        uids, iids, prevu, previ, tail2Order, compStart, hdr, NU, NV, out);
}